// Round 6
// baseline (238.279 us; speedup 1.0000x reference)
//
#include <hip/hip_runtime.h>

#define BB 8
#define CC 256
#define DD 128
#define NN 4096

#define LOG2E 1.44269504f
#define MSHIFT 32.0f  // fixed softmax shift (base-2 domain); |S*log2e| << 32 always

typedef __attribute__((ext_vector_type(8))) short short8;
typedef __attribute__((ext_vector_type(4))) short short4v;
typedef __attribute__((ext_vector_type(4))) float f32x4;
typedef __attribute__((ext_vector_type(16))) float f32x16;
typedef __attribute__((ext_vector_type(4))) unsigned int u32x4;

static __device__ __forceinline__ unsigned short f2bf(float f) {
    unsigned u = __builtin_bit_cast(unsigned, f);
    u += 0x7FFFu + ((u >> 16) & 1u);
    return (unsigned short)(u >> 16);
}
static __device__ __forceinline__ float bf2f(unsigned short h) {
    unsigned u = ((unsigned)h) << 16;
    return __builtin_bit_cast(float, u);
}
static __device__ __forceinline__ short8 pack8(float4 a, float4 b) {
    short8 r;
    r[0] = (short)f2bf(a.x); r[1] = (short)f2bf(a.y);
    r[2] = (short)f2bf(a.z); r[3] = (short)f2bf(a.w);
    r[4] = (short)f2bf(b.x); r[5] = (short)f2bf(b.y);
    r[6] = (short)f2bf(b.z); r[7] = (short)f2bf(b.w);
    return r;
}
// packed f32x2 -> bf16x2 (RNE); element 0 in low 16 bits
static __device__ __forceinline__ unsigned cvtpk_bf16(float lo, float hi) {
    unsigned r;
    asm("v_cvt_pk_bf16_f32 %0, %1, %2" : "=v"(r) : "v"(lo), "v"(hi));
    return r;
}
// swap upper 32 lanes of a with lower 32 lanes of b (T12 primitive)
static __device__ __forceinline__ void pl32swap(unsigned &a, unsigned &b) {
#if __has_builtin(__builtin_amdgcn_permlane32_swap)
    auto r = __builtin_amdgcn_permlane32_swap((int)a, (int)b, false, false);
    a = (unsigned)r[0]; b = (unsigned)r[1];
#else
    asm("v_permlane32_swap_b32 %0, %1" : "+v"(a), "+v"(b));
#endif
}

// ---------------- kernel 2: FUSED projections (x read ONCE; 3 MFMAs per B-frag) -------
// grid (NN/128, BB) = 256 blocks, block 512 = 8 waves; wave owns d-range (wave&3)*32,
// n-range (wave>>2)*64. Per kc chunk: stage x^T [128n][64c] bf16 into LDS (lane-contiguous
// fp32 reads, col swizzle (c + 8*(n>>4)) & 63), then accumulate theta/phi/g together.
// Outputs: Q=theta*log2e [n][d], K=phi [n][d], Vt=g [d][n]. Replaces 3 passes over x.
__global__ __launch_bounds__(512, 2) void k_proj(
        const float* __restrict__ x,
        const float* __restrict__ w_phi, const float* __restrict__ b_phi,
        const float* __restrict__ w_theta, const float* __restrict__ b_theta,
        const float* __restrict__ w_g, const float* __restrict__ b_g,
        unsigned short* __restrict__ qws, unsigned short* __restrict__ kws,
        unsigned short* __restrict__ vtws) {
    __shared__ __align__(16) unsigned short xs[128][72];     // staged x^T chunk (18432 B)
    __shared__ __align__(16) unsigned short rp[128][136];    // repack buffer (34816 B)
    int nb = blockIdx.x * 128, b = blockIdx.y;
    int t = threadIdx.x, lane = t & 63, wave = t >> 6;
    int l16 = lane & 15, l4 = lane >> 4;
    int wd = wave & 3, wn = wave >> 2;  // d-range wd*32, n-range wn*64

    f32x4 a_th[2][4], a_ph[2][4], a_g[2][4];
#pragma unroll
    for (int mf = 0; mf < 2; mf++)
#pragma unroll
        for (int nf = 0; nf < 4; nf++)
#pragma unroll
            for (int e = 0; e < 4; e++) { a_th[mf][nf][e] = 0.f; a_ph[mf][nf][e] = 0.f; a_g[mf][nf][e] = 0.f; }

    const float* xpb = x + (size_t)b * CC * NN;  // [c][n]

    for (int kc = 0; kc < 4; kc++) {
        int c0k = kc * 64;
        __syncthreads();
        {   // stage 64c x 128n: 2048 float4, lane-contiguous (1 KB/wave-instr)
            float4 xv[4];
#pragma unroll
            for (int j = 0; j < 4; j++) {
                int idx = t + 512 * j;
                int cr = idx >> 5, pos = idx & 31;
                xv[j] = *(const float4*)(xpb + (size_t)(c0k + cr) * NN + nb + pos * 4);
            }
#pragma unroll
            for (int j = 0; j < 4; j++) {
                int idx = t + 512 * j;
                int cr = idx >> 5, pos = idx & 31;
                int col = (cr + 8 * (pos >> 2)) & 63;
                xs[pos * 4 + 0][col] = f2bf(xv[j].x);
                xs[pos * 4 + 1][col] = f2bf(xv[j].y);
                xs[pos * 4 + 2][col] = f2bf(xv[j].z);
                xs[pos * 4 + 3][col] = f2bf(xv[j].w);
            }
        }
        __syncthreads();
        // weight A-frags for this c-chunk (L2-resident after first block)
        short8 af_t[2][2], af_p[2][2], af_g[2][2];  // [mf][ic]
#pragma unroll
        for (int mf = 0; mf < 2; mf++)
#pragma unroll
            for (int ic = 0; ic < 2; ic++) {
                int d = wd * 32 + mf * 16 + l16;
                int co = c0k + ic * 32 + l4 * 8;
                const float* wpt = w_theta + d * CC + co;
                const float* wpp = w_phi   + d * CC + co;
                const float* wpg = w_g     + d * CC + co;
                af_t[mf][ic] = pack8(*(const float4*)wpt, *(const float4*)(wpt + 4));
                af_p[mf][ic] = pack8(*(const float4*)wpp, *(const float4*)(wpp + 4));
                af_g[mf][ic] = pack8(*(const float4*)wpg, *(const float4*)(wpg + 4));
            }
#pragma unroll
        for (int nf = 0; nf < 4; nf++)
#pragma unroll
            for (int ic = 0; ic < 2; ic++) {
                int ncol = (ic * 32 + l4 * 8 + 8 * (wn * 4 + nf)) & 63;
                short8 bfr = *(const short8*)&xs[wn * 64 + nf * 16 + l16][ncol];
                a_th[0][nf] = __builtin_amdgcn_mfma_f32_16x16x32_bf16(af_t[0][ic], bfr, a_th[0][nf], 0, 0, 0);
                a_th[1][nf] = __builtin_amdgcn_mfma_f32_16x16x32_bf16(af_t[1][ic], bfr, a_th[1][nf], 0, 0, 0);
                a_ph[0][nf] = __builtin_amdgcn_mfma_f32_16x16x32_bf16(af_p[0][ic], bfr, a_ph[0][nf], 0, 0, 0);
                a_ph[1][nf] = __builtin_amdgcn_mfma_f32_16x16x32_bf16(af_p[1][ic], bfr, a_ph[1][nf], 0, 0, 0);
                a_g[0][nf]  = __builtin_amdgcn_mfma_f32_16x16x32_bf16(af_g[0][ic], bfr, a_g[0][nf], 0, 0, 0);
                a_g[1][nf]  = __builtin_amdgcn_mfma_f32_16x16x32_bf16(af_g[1][ic], bfr, a_g[1][nf], 0, 0, 0);
            }
    }
    // acc C-layout: col(l16) = n-within-frag, row(l4*4+r) = d-within-frag
    __syncthreads();  // xs reads done (rp disjoint, but keep phases clean)

    // ---- Q = theta * log2e, [n][d] ----
#pragma unroll
    for (int mf = 0; mf < 2; mf++) {
        int d0 = wd * 32 + mf * 16 + l4 * 4;
        float bb[4];
#pragma unroll
        for (int r = 0; r < 4; r++) bb[r] = b_theta[d0 + r];
#pragma unroll
        for (int nf = 0; nf < 4; nf++) {
            short4v pk;
#pragma unroll
            for (int r = 0; r < 4; r++) pk[r] = (short)f2bf((a_th[mf][nf][r] + bb[r]) * LOG2E);
            *(short4v*)&rp[wn * 64 + nf * 16 + l16][d0] = pk;
        }
    }
    __syncthreads();
    {
        unsigned short* outp = qws + (size_t)b * NN * DD;
#pragma unroll
        for (int i = 0; i < 4; i++) {
            int idx = t + 512 * i;
            int n = idx >> 4, dd = (idx & 15) * 8;
            *(short8*)(outp + (size_t)(nb + n) * DD + dd) = *(const short8*)&rp[n][dd];
        }
    }
    __syncthreads();

    // ---- K = phi, [n][d] ----
#pragma unroll
    for (int mf = 0; mf < 2; mf++) {
        int d0 = wd * 32 + mf * 16 + l4 * 4;
        float bb[4];
#pragma unroll
        for (int r = 0; r < 4; r++) bb[r] = b_phi[d0 + r];
#pragma unroll
        for (int nf = 0; nf < 4; nf++) {
            short4v pk;
#pragma unroll
            for (int r = 0; r < 4; r++) pk[r] = (short)f2bf(a_ph[mf][nf][r] + bb[r]);
            *(short4v*)&rp[wn * 64 + nf * 16 + l16][d0] = pk;
        }
    }
    __syncthreads();
    {
        unsigned short* outp = kws + (size_t)b * NN * DD;
#pragma unroll
        for (int i = 0; i < 4; i++) {
            int idx = t + 512 * i;
            int n = idx >> 4, dd = (idx & 15) * 8;
            *(short8*)(outp + (size_t)(nb + n) * DD + dd) = *(const short8*)&rp[n][dd];
        }
    }
    __syncthreads();

    // ---- Vt = g, [d][n] ----
#pragma unroll
    for (int mf = 0; mf < 2; mf++) {
        int drow = wd * 32 + mf * 16 + l4 * 4;
        float bb[4];
#pragma unroll
        for (int r = 0; r < 4; r++) bb[r] = b_g[drow + r];
#pragma unroll
        for (int nf = 0; nf < 4; nf++)
#pragma unroll
            for (int r = 0; r < 4; r++)
                rp[drow + r][wn * 64 + nf * 16 + l16] = f2bf(a_g[mf][nf][r] + bb[r]);
    }
    __syncthreads();
    {
        unsigned short* outp = vtws + (size_t)b * DD * NN;
#pragma unroll
        for (int i = 0; i < 4; i++) {
            int idx = t + 512 * i;
            int d = idx >> 4, n0s = (idx & 15) * 8;
            *(short8*)(outp + (size_t)d * NN + nb + n0s) = *(const short8*)&rp[d][n0s];
        }
    }
}

// ---------------- kernel 3: flash attention — 2-wave blocks, 32x32 MFMA, in-reg softmax ----
// (round-2 verified version: 110 us, MfmaUtil 27, no spill)
// grid 1024 = 8 b x 2 ks x 64 q-tiles (4 independent blocks/CU for latency hiding).
// Wave w owns 32 q-rows (qb + w*32 + l31). KVBLK = 32 keys/iter, NIT = 64.
// Swapped QK^T: S^T = mfma_32x32x16(K, Q) -> lane holds S[key][q=l31]; softmax lane-local;
// PV A-frags built in-register via cvt_pk_bf16 + permlane32_swap (T12).
// LDS: double-buffered K (32x256B, swz ^(row&7)) + V (128x64B, swz ^((row^row>>2)&3));
// ONE barrier per iter: issue loads(t+1) -> compute(t) -> write buf^1 -> barrier.
__global__ __launch_bounds__(128, 2) void k_flash(
        const unsigned short* __restrict__ q, const unsigned short* __restrict__ kk,
        const unsigned short* __restrict__ vt, unsigned short* __restrict__ opart,
        float* __restrict__ lsums) {
    __shared__ __align__(16) unsigned char smem[32768];
    // K[buf] at buf*8192 (32 rows x 256 B); V[buf] at 16384 + buf*8192 (128 rows x 64 B)

    int bid = blockIdx.x;
    int b   = bid & 7;           // batch -> XCD (round-robin dispatch): K/V L2-resident
    int rem = bid >> 3;
    int ks  = rem >> 6;
    int qt  = rem & 63;
    int qb  = qt * 64;

    int t = threadIdx.x, lane = t & 63, wave = t >> 6;
    int l31 = lane & 31, hi = lane >> 5;

    const unsigned short* qp = q  + (size_t)b * NN * DD;
    const unsigned short* kp = kk + (size_t)b * NN * DD;
    const unsigned short* vp = vt + (size_t)b * DD * NN;

    // Q fragments (B-operand of swapped QK^T): lane holds Q[qb+w*32+l31][kc*16+hi*8+e]
    short8 qreg[8];
    {
        int qrow = qb + wave * 32 + l31;
#pragma unroll
        for (int kc = 0; kc < 8; kc++)
            qreg[kc] = *(const short8*)(qp + (size_t)qrow * DD + kc * 16 + hi * 8);
    }

    f32x16 o[4];
#pragma unroll
    for (int df = 0; df < 4; df++)
#pragma unroll
        for (int e = 0; e < 16; e++) o[df][e] = 0.f;
    float lsum0 = 0.f, lsum1 = 0.f;

    int kbase = ks * (NN / 2);
    const int NIT = (NN / 2) / 32;  // 64

    // prologue: stage tile 0 into buffer 0
    {
        uint4 k0[4], v0[4];
#pragma unroll
        for (int i = 0; i < 4; i++) {
            int idx = t + 128 * i;  // 0..511
            k0[i] = *(const uint4*)(kp + (size_t)(kbase + (idx >> 4)) * DD + (idx & 15) * 8);
            v0[i] = *(const uint4*)(vp + (size_t)(idx >> 2) * NN + kbase + (idx & 3) * 8);
        }
#pragma unroll
        for (int i = 0; i < 4; i++) {
            int idx = t + 128 * i;
            int rk = idx >> 4, ck = idx & 15;
            *(uint4*)((char*)smem + rk * 256 + ((ck ^ (rk & 7)) << 4)) = k0[i];
            int rv = idx >> 2, cv = idx & 3;
            *(uint4*)((char*)smem + 16384 + rv * 64 + ((cv ^ ((rv ^ (rv >> 2)) & 3)) << 4)) = v0[i];
        }
    }
    __syncthreads();

    for (int it = 0; it < NIT; ++it) {
        char* Kb  = (char*)smem + (it & 1) * 8192;
        char* Vb  = (char*)smem + 16384 + (it & 1) * 8192;
        char* Kb2 = (char*)smem + ((it & 1) ^ 1) * 8192;
        char* Vb2 = (char*)smem + 16384 + (((it & 1) ^ 1)) * 8192;

        // T14: issue next tile's global loads; latency hides under the 16 MFMAs below
        uint4 kreg[4], vreg[4];
        bool pf = (it + 1 < NIT);
        if (pf) {
            int mb2 = kbase + (it + 1) * 32;
#pragma unroll
            for (int i = 0; i < 4; i++) {
                int idx = t + 128 * i;
                kreg[i] = *(const uint4*)(kp + (size_t)(mb2 + (idx >> 4)) * DD + (idx & 15) * 8);
                vreg[i] = *(const uint4*)(vp + (size_t)(idx >> 2) * NN + mb2 + (idx & 3) * 8);
            }
        }

        // S^T = K . Q^T - 32 (two interleaved accumulators -> MFMA dep-distance 2)
        f32x16 sA, sB;
#pragma unroll
        for (int e = 0; e < 16; e++) { sA[e] = -MSHIFT; sB[e] = 0.f; }
        __builtin_amdgcn_s_setprio(1);
#pragma unroll
        for (int kc = 0; kc < 8; kc += 2) {
            short8 a0 = *(const short8*)(Kb + l31 * 256 + ((((kc << 1) | hi) ^ (l31 & 7)) << 4));
            short8 a1 = *(const short8*)(Kb + l31 * 256 + (((((kc + 1) << 1) | hi) ^ (l31 & 7)) << 4));
            sA = __builtin_amdgcn_mfma_f32_32x32x16_bf16(a0, qreg[kc], sA, 0, 0, 0);
            sB = __builtin_amdgcn_mfma_f32_32x32x16_bf16(a1, qreg[kc + 1], sB, 0, 0, 0);
        }
        __builtin_amdgcn_s_setprio(0);

        // p = exp2(s'); lane-local row partials; PV A-frags in-register (T12)
        u32x4 pa[2];
        {
            float p[16];
#pragma unroll
            for (int r = 0; r < 16; r++) {
                p[r] = __builtin_exp2f(sA[r] + sB[r]);
                if (r & 1) lsum1 += p[r]; else lsum0 += p[r];
            }
#pragma unroll
            for (int h = 0; h < 2; h++) {
                unsigned a0 = cvtpk_bf16(p[8 * h + 0], p[8 * h + 1]);
                unsigned a1 = cvtpk_bf16(p[8 * h + 2], p[8 * h + 3]);
                unsigned b0 = cvtpk_bf16(p[8 * h + 4], p[8 * h + 5]);
                unsigned b1 = cvtpk_bf16(p[8 * h + 6], p[8 * h + 7]);
                pl32swap(a0, b0);
                pl32swap(a1, b1);
                u32x4 v; v[0] = a0; v[1] = a1; v[2] = b0; v[3] = b1;
                pa[h] = v;
            }
        }

        // O += P V  (V^T stored -> B-frag is a direct contiguous ds_read_b128)
        __builtin_amdgcn_s_setprio(1);
#pragma unroll
        for (int df = 0; df < 4; df++) {
            int row = df * 32 + l31;
            int sw = (row ^ (row >> 2)) & 3;
#pragma unroll
            for (int c = 0; c < 2; c++) {
                short8 vb = *(const short8*)(Vb + row * 64 + ((((c << 1) | hi) ^ sw) << 4));
                o[df] = __builtin_amdgcn_mfma_f32_32x32x16_bf16(
                    __builtin_bit_cast(short8, pa[c]), vb, o[df], 0, 0, 0);
            }
        }
        __builtin_amdgcn_s_setprio(0);

        // write prefetched tile to the other buffer; compiler inserts the vmcnt waits
        if (pf) {
#pragma unroll
            for (int i = 0; i < 4; i++) {
                int idx = t + 128 * i;
                int rk = idx >> 4, ck = idx & 15;
                *(uint4*)(Kb2 + rk * 256 + ((ck ^ (rk & 7)) << 4)) = kreg[i];
                int rv = idx >> 2, cv = idx & 3;
                *(uint4*)(Vb2 + rv * 64 + ((cv ^ ((rv ^ (rv >> 2)) & 3)) << 4)) = vreg[i];
            }
        }
        __syncthreads();  // buf[cur] free for iter t+1's writes; buf[cur^1] ready
    }

    // ---- epilogue: row-sums + staged coalesced O-partial store ----
    {
        float lsum = lsum0 + lsum1;
        float tot = lsum + __shfl_xor(lsum, 32);
        if (lane < 32)
            lsums[((size_t)ks * BB + b) * NN + qb + wave * 32 + l31] = tot;
    }
    unsigned short (*Ox)[136] = (unsigned short (*)[136])smem;  // 64 x 136 (17408 B)
#pragma unroll
    for (int df = 0; df < 4; df++)
#pragma unroll
        for (int r = 0; r < 16; r++) {
            int qr = (r & 3) + 8 * (r >> 2) + 4 * hi;
            Ox[wave * 32 + qr][df * 32 + l31] = f2bf(o[df][r]);
        }
    __syncthreads();
    unsigned short* op = opart + (((size_t)ks * BB + b) * NN + qb) * DD;
#pragma unroll
    for (int i = 0; i < 8; i++) {
        int idx = t + 128 * i;  // 0..1023
        int nr = idx >> 4, c0 = (idx & 15) * 8;
        *(short8*)(op + (size_t)nr * DD + c0) = *(const short8*)&Ox[nr][c0];
    }
}

// ---------------- kernel 4: combine partials + out = w_mask . y^T + b_mask + x ----------------
// grid (NN/64, BB), block 256; BOTH c-halves per block (opart/Ys staged once, cs loop).
// Ys and Os are disjoint LDS regions (52.5 KB total) -> 2 blocks/CU.
__global__ __launch_bounds__(256) void k_maskout(
        const unsigned short* __restrict__ opart, const float* __restrict__ lsums,
        const float* __restrict__ w_mask, const float* __restrict__ b_mask,
        const float* __restrict__ x, float* __restrict__ out) {
    __shared__ __align__(16) unsigned char pool[52480];
    unsigned short (*Ys)[136] = (unsigned short (*)[136])pool;   // 64x136x2B = 17408
    float (*Os)[68] = (float (*)[68])(pool + 17408);             // 128x68x4B = 34816
    float* invl = (float*)(pool + 52224);                        // 256 B
    int nb = blockIdx.x * 64, b = blockIdx.y;
    int t = threadIdx.x, lane = t & 63, wave = t >> 6;
    int l16 = lane & 15, l4 = lane >> 4;

    const unsigned short* o0 = opart + ((size_t)b * NN + nb) * DD;
    const unsigned short* o1 = opart + (((size_t)BB + b) * NN + nb) * DD;
    if (t < 64) {
        float ls0 = lsums[(size_t)b * NN + nb + t];
        float ls1 = lsums[((size_t)BB + b) * NN + nb + t];
        invl[t] = 1.0f / (ls0 + ls1);
    }
    __syncthreads();
#pragma unroll
    for (int i = 0; i < 4; i++) {  // combine the 2 key-split partials while staging y
        int idx = t + 256 * i;
        int nr = idx >> 4, d0 = (idx & 15) * 8;
        short8 a = *(const short8*)(o0 + (size_t)nr * DD + d0);
        short8 c = *(const short8*)(o1 + (size_t)nr * DD + d0);
        float inv = invl[nr];
        short8 yv;
#pragma unroll
        for (int j = 0; j < 8; j++)
            yv[j] = (short)f2bf((bf2f((unsigned short)a[j]) + bf2f((unsigned short)c[j])) * inv);
        *(short8*)&Ys[nr][d0] = yv;
    }
    __syncthreads();

    for (int cs = 0; cs < 2; cs++) {
        f32x4 acc[2][4];
#pragma unroll
        for (int mf = 0; mf < 2; mf++)
#pragma unroll
            for (int nf = 0; nf < 4; nf++)
#pragma unroll
                for (int e = 0; e < 4; e++) acc[mf][nf][e] = 0.f;

#pragma unroll
        for (int kc = 0; kc < 4; kc++) {
            int d0 = kc * 32 + l4 * 8;
            short8 af[2];
#pragma unroll
            for (int mf = 0; mf < 2; mf++) {
                int c = cs * 128 + wave * 32 + mf * 16 + l16;
                const float* wp = w_mask + c * DD + d0;
                af[mf] = pack8(*(const float4*)wp, *(const float4*)(wp + 4));
            }
#pragma unroll
            for (int nf = 0; nf < 4; nf++) {
                short8 bfr = *(const short8*)&Ys[nf * 16 + l16][d0];
#pragma unroll
                for (int mf = 0; mf < 2; mf++)
                    acc[mf][nf] = __builtin_amdgcn_mfma_f32_16x16x32_bf16(af[mf], bfr, acc[mf][nf], 0, 0, 0);
            }
        }
        __syncthreads();  // cs=1: previous epilogue's Os reads done (no-op cost at cs=0)

        // stage acc + bias into Os[128][68] fp32
#pragma unroll
        for (int mf = 0; mf < 2; mf++) {
            int c0 = wave * 32 + mf * 16 + l4 * 4;  // local c 0..127
            float bb[4];
#pragma unroll
            for (int r = 0; r < 4; r++) bb[r] = b_mask[cs * 128 + c0 + r];
#pragma unroll
            for (int r = 0; r < 4; r++)
#pragma unroll
                for (int nf = 0; nf < 4; nf++)
                    Os[c0 + r][nf * 16 + l16] = acc[mf][nf][r] + bb[r];
        }
        __syncthreads();

        // vectorized epilogue: out = Os + x (float4; 256B contiguous per c-row)
        const float* xp = x + (size_t)b * CC * NN + (size_t)cs * 128 * NN + nb;
        float* op = out + (size_t)b * CC * NN + (size_t)cs * 128 * NN + nb;
#pragma unroll
        for (int i = 0; i < 8; i++) {
            int idx = t + 256 * i;        // 0..2047
            int c = idx >> 4, nq = (idx & 15) * 4;
            float4 osv = *(const float4*)&Os[c][nq];
            float4 xv = *(const float4*)(xp + (size_t)c * NN + nq);
            float4 ov;
            ov.x = osv.x + xv.x; ov.y = osv.y + xv.y;
            ov.z = osv.z + xv.z; ov.w = osv.w + xv.w;
            *(float4*)(op + (size_t)c * NN + nq) = ov;
        }
    }
}

extern "C" void kernel_launch(void* const* d_in, const int* in_sizes, int n_in,
                              void* d_out, int out_size, void* d_ws, size_t ws_size,
                              hipStream_t stream) {
    const float* x       = (const float*)d_in[0];
    const float* w_phi   = (const float*)d_in[1];
    const float* b_phi   = (const float*)d_in[2];
    const float* w_theta = (const float*)d_in[3];
    const float* b_theta = (const float*)d_in[4];
    const float* w_g     = (const float*)d_in[5];
    const float* b_g     = (const float*)d_in[6];
    const float* w_mask  = (const float*)d_in[7];
    const float* b_mask  = (const float*)d_in[8];
    float* out = (float*)d_out;

    // ws (48 MiB): [0,16M): Opart (2*8*4096*128 bf16 = 16 MiB)
    //              [16,24M): Q | [24,32M): K | [32,40M): Vt | [40M+): lsums (256 KiB)
    char* ws = (char*)d_ws;
    unsigned short* opart = (unsigned short*)(ws);
    unsigned short* qw    = (unsigned short*)(ws + ((size_t)16 << 20));
    unsigned short* kw    = (unsigned short*)(ws + ((size_t)24 << 20));
    unsigned short* vtw   = (unsigned short*)(ws + ((size_t)32 << 20));
    float*          lsums = (float*)(ws + ((size_t)40 << 20));

    k_proj<<<dim3(NN / 128, BB), 512, 0, stream>>>(x, w_phi, b_phi, w_theta, b_theta,
                                                   w_g, b_g, qw, kw, vtw);
    k_flash<<<dim3(1024, 1, 1), 128, 0, stream>>>(qw, kw, vtw, opart, lsums);
    k_maskout<<<dim3(NN / 64, BB), 256, 0, stream>>>(opart, lsums, w_mask, b_mask, x, out);
}

// Round 7
// 233.793 us; speedup vs baseline: 1.0192x; 1.0192x over previous
//
#include <hip/hip_runtime.h>

#define BB 8
#define CC 256
#define DD 128
#define NN 4096

#define LOG2E 1.44269504f
#define MSHIFT 32.0f  // fixed softmax shift (base-2 domain); |S*log2e| << 32 always

typedef __attribute__((ext_vector_type(8))) short short8;
typedef __attribute__((ext_vector_type(4))) short short4v;
typedef __attribute__((ext_vector_type(4))) float f32x4;
typedef __attribute__((ext_vector_type(16))) float f32x16;
typedef __attribute__((ext_vector_type(4))) unsigned int u32x4;

static __device__ __forceinline__ unsigned short f2bf(float f) {
    unsigned u = __builtin_bit_cast(unsigned, f);
    u += 0x7FFFu + ((u >> 16) & 1u);
    return (unsigned short)(u >> 16);
}
static __device__ __forceinline__ float bf2f(unsigned short h) {
    unsigned u = ((unsigned)h) << 16;
    return __builtin_bit_cast(float, u);
}
static __device__ __forceinline__ short8 pack8(float4 a, float4 b) {
    short8 r;
    r[0] = (short)f2bf(a.x); r[1] = (short)f2bf(a.y);
    r[2] = (short)f2bf(a.z); r[3] = (short)f2bf(a.w);
    r[4] = (short)f2bf(b.x); r[5] = (short)f2bf(b.y);
    r[6] = (short)f2bf(b.z); r[7] = (short)f2bf(b.w);
    return r;
}
// packed f32x2 -> bf16x2 (RNE); element 0 in low 16 bits
static __device__ __forceinline__ unsigned cvtpk_bf16(float lo, float hi) {
    unsigned r;
    asm("v_cvt_pk_bf16_f32 %0, %1, %2" : "=v"(r) : "v"(lo), "v"(hi));
    return r;
}
// swap upper 32 lanes of a with lower 32 lanes of b (T12 primitive)
static __device__ __forceinline__ void pl32swap(unsigned &a, unsigned &b) {
#if __has_builtin(__builtin_amdgcn_permlane32_swap)
    auto r = __builtin_amdgcn_permlane32_swap((int)a, (int)b, false, false);
    a = (unsigned)r[0]; b = (unsigned)r[1];
#else
    asm("v_permlane32_swap_b32 %0, %1" : "+v"(a), "+v"(b));
#endif
}
// async global->LDS DMA, 16 B/lane: LDS dest = wave-uniform base + lane*16 (m97/m104)
static __device__ __forceinline__ void gll16(const void* g, void* l) {
    __builtin_amdgcn_global_load_lds(
        (const __attribute__((address_space(1))) unsigned int*)g,
        (__attribute__((address_space(3))) unsigned int*)l, 16, 0, 0);
}

// ---------------- kernel 2: FUSED projections (x read ONCE; 3 MFMAs per B-frag) -------
// grid (NN/128, BB) = 256 blocks, block 512 = 8 waves; wave owns d-range (wave&3)*32,
// n-range (wave>>2)*64. Per kc chunk: stage x^T [128n][64c] bf16 into LDS (lane-contiguous
// fp32 reads, col swizzle (c + 8*(n>>4)) & 63), then accumulate theta/phi/g together.
// Outputs: Q=theta*log2e [n][d], K=phi [n][d], Vt=g [d][n]. Replaces 3 passes over x.
__global__ __launch_bounds__(512, 2) void k_proj(
        const float* __restrict__ x,
        const float* __restrict__ w_phi, const float* __restrict__ b_phi,
        const float* __restrict__ w_theta, const float* __restrict__ b_theta,
        const float* __restrict__ w_g, const float* __restrict__ b_g,
        unsigned short* __restrict__ qws, unsigned short* __restrict__ kws,
        unsigned short* __restrict__ vtws) {
    __shared__ __align__(16) unsigned short xs[128][72];     // staged x^T chunk (18432 B)
    __shared__ __align__(16) unsigned short rp[128][136];    // repack buffer (34816 B)
    int nb = blockIdx.x * 128, b = blockIdx.y;
    int t = threadIdx.x, lane = t & 63, wave = t >> 6;
    int l16 = lane & 15, l4 = lane >> 4;
    int wd = wave & 3, wn = wave >> 2;  // d-range wd*32, n-range wn*64

    f32x4 a_th[2][4], a_ph[2][4], a_g[2][4];
#pragma unroll
    for (int mf = 0; mf < 2; mf++)
#pragma unroll
        for (int nf = 0; nf < 4; nf++)
#pragma unroll
            for (int e = 0; e < 4; e++) { a_th[mf][nf][e] = 0.f; a_ph[mf][nf][e] = 0.f; a_g[mf][nf][e] = 0.f; }

    const float* xpb = x + (size_t)b * CC * NN;  // [c][n]

    for (int kc = 0; kc < 4; kc++) {
        int c0k = kc * 64;
        __syncthreads();
        {   // stage 64c x 128n: 2048 float4, lane-contiguous (1 KB/wave-instr)
            float4 xv[4];
#pragma unroll
            for (int j = 0; j < 4; j++) {
                int idx = t + 512 * j;
                int cr = idx >> 5, pos = idx & 31;
                xv[j] = *(const float4*)(xpb + (size_t)(c0k + cr) * NN + nb + pos * 4);
            }
#pragma unroll
            for (int j = 0; j < 4; j++) {
                int idx = t + 512 * j;
                int cr = idx >> 5, pos = idx & 31;
                int col = (cr + 8 * (pos >> 2)) & 63;
                xs[pos * 4 + 0][col] = f2bf(xv[j].x);
                xs[pos * 4 + 1][col] = f2bf(xv[j].y);
                xs[pos * 4 + 2][col] = f2bf(xv[j].z);
                xs[pos * 4 + 3][col] = f2bf(xv[j].w);
            }
        }
        __syncthreads();
        // weight A-frags for this c-chunk (L2-resident after first block)
        short8 af_t[2][2], af_p[2][2], af_g[2][2];  // [mf][ic]
#pragma unroll
        for (int mf = 0; mf < 2; mf++)
#pragma unroll
            for (int ic = 0; ic < 2; ic++) {
                int d = wd * 32 + mf * 16 + l16;
                int co = c0k + ic * 32 + l4 * 8;
                const float* wpt = w_theta + d * CC + co;
                const float* wpp = w_phi   + d * CC + co;
                const float* wpg = w_g     + d * CC + co;
                af_t[mf][ic] = pack8(*(const float4*)wpt, *(const float4*)(wpt + 4));
                af_p[mf][ic] = pack8(*(const float4*)wpp, *(const float4*)(wpp + 4));
                af_g[mf][ic] = pack8(*(const float4*)wpg, *(const float4*)(wpg + 4));
            }
#pragma unroll
        for (int nf = 0; nf < 4; nf++)
#pragma unroll
            for (int ic = 0; ic < 2; ic++) {
                int ncol = (ic * 32 + l4 * 8 + 8 * (wn * 4 + nf)) & 63;
                short8 bfr = *(const short8*)&xs[wn * 64 + nf * 16 + l16][ncol];
                a_th[0][nf] = __builtin_amdgcn_mfma_f32_16x16x32_bf16(af_t[0][ic], bfr, a_th[0][nf], 0, 0, 0);
                a_th[1][nf] = __builtin_amdgcn_mfma_f32_16x16x32_bf16(af_t[1][ic], bfr, a_th[1][nf], 0, 0, 0);
                a_ph[0][nf] = __builtin_amdgcn_mfma_f32_16x16x32_bf16(af_p[0][ic], bfr, a_ph[0][nf], 0, 0, 0);
                a_ph[1][nf] = __builtin_amdgcn_mfma_f32_16x16x32_bf16(af_p[1][ic], bfr, a_ph[1][nf], 0, 0, 0);
                a_g[0][nf]  = __builtin_amdgcn_mfma_f32_16x16x32_bf16(af_g[0][ic], bfr, a_g[0][nf], 0, 0, 0);
                a_g[1][nf]  = __builtin_amdgcn_mfma_f32_16x16x32_bf16(af_g[1][ic], bfr, a_g[1][nf], 0, 0, 0);
            }
    }
    // acc C-layout: col(l16) = n-within-frag, row(l4*4+r) = d-within-frag
    __syncthreads();  // xs reads done (rp disjoint, but keep phases clean)

    // ---- Q = theta * log2e, [n][d] ----
#pragma unroll
    for (int mf = 0; mf < 2; mf++) {
        int d0 = wd * 32 + mf * 16 + l4 * 4;
        float bb[4];
#pragma unroll
        for (int r = 0; r < 4; r++) bb[r] = b_theta[d0 + r];
#pragma unroll
        for (int nf = 0; nf < 4; nf++) {
            short4v pk;
#pragma unroll
            for (int r = 0; r < 4; r++) pk[r] = (short)f2bf((a_th[mf][nf][r] + bb[r]) * LOG2E);
            *(short4v*)&rp[wn * 64 + nf * 16 + l16][d0] = pk;
        }
    }
    __syncthreads();
    {
        unsigned short* outp = qws + (size_t)b * NN * DD;
#pragma unroll
        for (int i = 0; i < 4; i++) {
            int idx = t + 512 * i;
            int n = idx >> 4, dd = (idx & 15) * 8;
            *(short8*)(outp + (size_t)(nb + n) * DD + dd) = *(const short8*)&rp[n][dd];
        }
    }
    __syncthreads();

    // ---- K = phi, [n][d] ----
#pragma unroll
    for (int mf = 0; mf < 2; mf++) {
        int d0 = wd * 32 + mf * 16 + l4 * 4;
        float bb[4];
#pragma unroll
        for (int r = 0; r < 4; r++) bb[r] = b_phi[d0 + r];
#pragma unroll
        for (int nf = 0; nf < 4; nf++) {
            short4v pk;
#pragma unroll
            for (int r = 0; r < 4; r++) pk[r] = (short)f2bf(a_ph[mf][nf][r] + bb[r]);
            *(short4v*)&rp[wn * 64 + nf * 16 + l16][d0] = pk;
        }
    }
    __syncthreads();
    {
        unsigned short* outp = kws + (size_t)b * NN * DD;
#pragma unroll
        for (int i = 0; i < 4; i++) {
            int idx = t + 512 * i;
            int n = idx >> 4, dd = (idx & 15) * 8;
            *(short8*)(outp + (size_t)(nb + n) * DD + dd) = *(const short8*)&rp[n][dd];
        }
    }
    __syncthreads();

    // ---- Vt = g, [d][n] ----
#pragma unroll
    for (int mf = 0; mf < 2; mf++) {
        int drow = wd * 32 + mf * 16 + l4 * 4;
        float bb[4];
#pragma unroll
        for (int r = 0; r < 4; r++) bb[r] = b_g[drow + r];
#pragma unroll
        for (int nf = 0; nf < 4; nf++)
#pragma unroll
            for (int r = 0; r < 4; r++)
                rp[drow + r][wn * 64 + nf * 16 + l16] = f2bf(a_g[mf][nf][r] + bb[r]);
    }
    __syncthreads();
    {
        unsigned short* outp = vtws + (size_t)b * DD * NN;
#pragma unroll
        for (int i = 0; i < 4; i++) {
            int idx = t + 512 * i;
            int d = idx >> 4, n0s = (idx & 15) * 8;
            *(short8*)(outp + (size_t)d * NN + nb + n0s) = *(const short8*)&rp[d][n0s];
        }
    }
}

// ---------------- kernel 3: flash attention — 2-wave blocks, DMA-staged K/V ----------------
// r2-verified math/schedule; staging now via global_load_lds (16 B) with PRE-SWIZZLED
// global source addresses (m173 pattern): LDS dest linear, src chunk XOR'd, so the LDS
// image is bit-identical to the old reg-staged swizzled layout — all ds_reads unchanged.
// Removes 8 VMEM-reg loads + 8 swizzled ds_writes + ~24 VALU per wave-iter and the
// 32-VGPR prefetch state. One barrier/iter (its vmcnt(0) drain completes the DMA).
// grid 1024 = 8 b x 2 ks x 64 q-tiles (4 blocks/CU). Wave owns 32 q-rows. KVBLK=32.
__global__ __launch_bounds__(128, 2) void k_flash(
        const unsigned short* __restrict__ q, const unsigned short* __restrict__ kk,
        const unsigned short* __restrict__ vt, unsigned short* __restrict__ opart,
        float* __restrict__ lsums) {
    __shared__ __align__(16) unsigned char smem[32768];
    // K[buf] at buf*8192 (32 rows x 256 B); V[buf] at 16384 + buf*8192 (128 rows x 64 B)

    int bid = blockIdx.x;
    int b   = bid & 7;           // batch -> XCD (round-robin dispatch): K/V L2-resident
    int rem = bid >> 3;
    int ks  = rem >> 6;
    int qt  = rem & 63;
    int qb  = qt * 64;

    int t = threadIdx.x, lane = t & 63, wave = t >> 6;
    int l31 = lane & 31, hi = lane >> 5;

    const unsigned short* qp = q  + (size_t)b * NN * DD;
    const unsigned short* kp = kk + (size_t)b * NN * DD;
    const unsigned short* vp = vt + (size_t)b * DD * NN;

    // Q fragments (B-operand of swapped QK^T): lane holds Q[qb+w*32+l31][kc*16+hi*8+e]
    short8 qreg[8];
    {
        int qrow = qb + wave * 32 + l31;
#pragma unroll
        for (int kc = 0; kc < 8; kc++)
            qreg[kc] = *(const short8*)(qp + (size_t)qrow * DD + kc * 16 + hi * 8);
    }

    // per-lane DMA source offsets (elements) for this wave's 4 K-segs + 4 V-segs.
    // K seg covers rows 4s..4s+4 (lane>>4 = row-in-seg, lane&15 = dest chunk c');
    // src chunk = c' ^ (row&7)  ->  LDS[row][c'] = G[row][c'^(row&7)]  (old layout).
    // V seg covers d-rows 16s..16s+16 (lane>>2 = row-in-seg, lane&3 = dest chunk);
    // src chunk = c' ^ ((row^(row>>2))&3).
    int koff[4], voff[4];
#pragma unroll
    for (int j = 0; j < 4; j++) {
        int seg = wave * 4 + j;
        int krow = seg * 4 + (lane >> 4);
        koff[j] = krow * DD + (((lane & 15) ^ (krow & 7)) << 3);
        int vrow = seg * 16 + (lane >> 2);
        voff[j] = vrow * NN + (((lane & 3) ^ ((vrow ^ (vrow >> 2)) & 3)) << 3);
    }

    f32x16 o[4];
#pragma unroll
    for (int df = 0; df < 4; df++)
#pragma unroll
        for (int e = 0; e < 16; e++) o[df][e] = 0.f;
    float lsum0 = 0.f, lsum1 = 0.f;

    int kbase = ks * (NN / 2);
    const int NIT = (NN / 2) / 32;  // 64

    // prologue: DMA tile 0 into buffer 0
#pragma unroll
    for (int j = 0; j < 4; j++) {
        int seg = wave * 4 + j;
        gll16(kp + (size_t)kbase * DD + koff[j], (char*)smem + seg * 1024);
        gll16(vp + kbase + voff[j], (char*)smem + 16384 + seg * 1024);
    }
    __syncthreads();  // drains vmcnt -> tile 0 resident

    for (int it = 0; it < NIT; ++it) {
        char* Kb = (char*)smem + (it & 1) * 8192;
        char* Vb = (char*)smem + 16384 + (it & 1) * 8192;

        // T14/DMA: issue next tile's global_load_lds into the free buffer; latency
        // hides under the 24 MFMAs + softmax below; end-of-iter barrier drains it.
        if (it + 1 < NIT) {
            int mb2 = kbase + (it + 1) * 32;
            int bp = (it & 1) ^ 1;
#pragma unroll
            for (int j = 0; j < 4; j++) {
                int seg = wave * 4 + j;
                gll16(kp + (size_t)mb2 * DD + koff[j], (char*)smem + bp * 8192 + seg * 1024);
                gll16(vp + mb2 + voff[j], (char*)smem + 16384 + bp * 8192 + seg * 1024);
            }
        }

        // S^T = K . Q^T - 32 (two interleaved accumulators -> MFMA dep-distance 2)
        f32x16 sA, sB;
#pragma unroll
        for (int e = 0; e < 16; e++) { sA[e] = -MSHIFT; sB[e] = 0.f; }
        __builtin_amdgcn_s_setprio(1);
#pragma unroll
        for (int kc = 0; kc < 8; kc += 2) {
            short8 a0 = *(const short8*)(Kb + l31 * 256 + ((((kc << 1) | hi) ^ (l31 & 7)) << 4));
            short8 a1 = *(const short8*)(Kb + l31 * 256 + (((((kc + 1) << 1) | hi) ^ (l31 & 7)) << 4));
            sA = __builtin_amdgcn_mfma_f32_32x32x16_bf16(a0, qreg[kc], sA, 0, 0, 0);
            sB = __builtin_amdgcn_mfma_f32_32x32x16_bf16(a1, qreg[kc + 1], sB, 0, 0, 0);
        }
        __builtin_amdgcn_s_setprio(0);

        // p = exp2(s'); lane-local row partials; PV A-frags in-register (T12)
        u32x4 pa[2];
        {
            float p[16];
#pragma unroll
            for (int r = 0; r < 16; r++) {
                p[r] = __builtin_exp2f(sA[r] + sB[r]);
                if (r & 1) lsum1 += p[r]; else lsum0 += p[r];
            }
#pragma unroll
            for (int h = 0; h < 2; h++) {
                unsigned a0 = cvtpk_bf16(p[8 * h + 0], p[8 * h + 1]);
                unsigned a1 = cvtpk_bf16(p[8 * h + 2], p[8 * h + 3]);
                unsigned b0 = cvtpk_bf16(p[8 * h + 4], p[8 * h + 5]);
                unsigned b1 = cvtpk_bf16(p[8 * h + 6], p[8 * h + 7]);
                pl32swap(a0, b0);
                pl32swap(a1, b1);
                u32x4 v; v[0] = a0; v[1] = a1; v[2] = b0; v[3] = b1;
                pa[h] = v;
            }
        }

        // O += P V  (V^T stored -> B-frag is a direct contiguous ds_read_b128)
        __builtin_amdgcn_s_setprio(1);
#pragma unroll
        for (int df = 0; df < 4; df++) {
            int row = df * 32 + l31;
            int sw = (row ^ (row >> 2)) & 3;
#pragma unroll
            for (int c = 0; c < 2; c++) {
                short8 vb = *(const short8*)(Vb + row * 64 + ((((c << 1) | hi) ^ sw) << 4));
                o[df] = __builtin_amdgcn_mfma_f32_32x32x16_bf16(
                    __builtin_bit_cast(short8, pa[c]), vb, o[df], 0, 0, 0);
            }
        }
        __builtin_amdgcn_s_setprio(0);

        __syncthreads();  // all reads of tile it done; vmcnt(0) drain -> tile it+1 ready
    }

    // ---- epilogue: row-sums + staged coalesced O-partial store ----
    {
        float lsum = lsum0 + lsum1;
        float tot = lsum + __shfl_xor(lsum, 32);
        if (lane < 32)
            lsums[((size_t)ks * BB + b) * NN + qb + wave * 32 + l31] = tot;
    }
    unsigned short (*Ox)[136] = (unsigned short (*)[136])smem;  // 64 x 136 (17408 B)
#pragma unroll
    for (int df = 0; df < 4; df++)
#pragma unroll
        for (int r = 0; r < 16; r++) {
            int qr = (r & 3) + 8 * (r >> 2) + 4 * hi;
            Ox[wave * 32 + qr][df * 32 + l31] = f2bf(o[df][r]);
        }
    __syncthreads();
    unsigned short* op = opart + (((size_t)ks * BB + b) * NN + qb) * DD;
#pragma unroll
    for (int i = 0; i < 8; i++) {
        int idx = t + 128 * i;  // 0..1023
        int nr = idx >> 4, c0 = (idx & 15) * 8;
        *(short8*)(op + (size_t)nr * DD + c0) = *(const short8*)&Ox[nr][c0];
    }
}

// ---------------- kernel 4: combine partials + out = w_mask . y^T + b_mask + x ----------------
// grid (NN/64, BB), block 256; BOTH c-halves per block (opart/Ys staged once, cs loop).
// Ys and Os are disjoint LDS regions (52.5 KB total) -> 2 blocks/CU.
__global__ __launch_bounds__(256) void k_maskout(
        const unsigned short* __restrict__ opart, const float* __restrict__ lsums,
        const float* __restrict__ w_mask, const float* __restrict__ b_mask,
        const float* __restrict__ x, float* __restrict__ out) {
    __shared__ __align__(16) unsigned char pool[52480];
    unsigned short (*Ys)[136] = (unsigned short (*)[136])pool;   // 64x136x2B = 17408
    float (*Os)[68] = (float (*)[68])(pool + 17408);             // 128x68x4B = 34816
    float* invl = (float*)(pool + 52224);                        // 256 B
    int nb = blockIdx.x * 64, b = blockIdx.y;
    int t = threadIdx.x, lane = t & 63, wave = t >> 6;
    int l16 = lane & 15, l4 = lane >> 4;

    const unsigned short* o0 = opart + ((size_t)b * NN + nb) * DD;
    const unsigned short* o1 = opart + (((size_t)BB + b) * NN + nb) * DD;
    if (t < 64) {
        float ls0 = lsums[(size_t)b * NN + nb + t];
        float ls1 = lsums[((size_t)BB + b) * NN + nb + t];
        invl[t] = 1.0f / (ls0 + ls1);
    }
    __syncthreads();
#pragma unroll
    for (int i = 0; i < 4; i++) {  // combine the 2 key-split partials while staging y
        int idx = t + 256 * i;
        int nr = idx >> 4, d0 = (idx & 15) * 8;
        short8 a = *(const short8*)(o0 + (size_t)nr * DD + d0);
        short8 c = *(const short8*)(o1 + (size_t)nr * DD + d0);
        float inv = invl[nr];
        short8 yv;
#pragma unroll
        for (int j = 0; j < 8; j++)
            yv[j] = (short)f2bf((bf2f((unsigned short)a[j]) + bf2f((unsigned short)c[j])) * inv);
        *(short8*)&Ys[nr][d0] = yv;
    }
    __syncthreads();

    for (int cs = 0; cs < 2; cs++) {
        f32x4 acc[2][4];
#pragma unroll
        for (int mf = 0; mf < 2; mf++)
#pragma unroll
            for (int nf = 0; nf < 4; nf++)
#pragma unroll
                for (int e = 0; e < 4; e++) acc[mf][nf][e] = 0.f;

#pragma unroll
        for (int kc = 0; kc < 4; kc++) {
            int d0 = kc * 32 + l4 * 8;
            short8 af[2];
#pragma unroll
            for (int mf = 0; mf < 2; mf++) {
                int c = cs * 128 + wave * 32 + mf * 16 + l16;
                const float* wp = w_mask + c * DD + d0;
                af[mf] = pack8(*(const float4*)wp, *(const float4*)(wp + 4));
            }
#pragma unroll
            for (int nf = 0; nf < 4; nf++) {
                short8 bfr = *(const short8*)&Ys[nf * 16 + l16][d0];
#pragma unroll
                for (int mf = 0; mf < 2; mf++)
                    acc[mf][nf] = __builtin_amdgcn_mfma_f32_16x16x32_bf16(af[mf], bfr, acc[mf][nf], 0, 0, 0);
            }
        }
        __syncthreads();  // cs=1: previous epilogue's Os reads done (no-op cost at cs=0)

        // stage acc + bias into Os[128][68] fp32
#pragma unroll
        for (int mf = 0; mf < 2; mf++) {
            int c0 = wave * 32 + mf * 16 + l4 * 4;  // local c 0..127
            float bb[4];
#pragma unroll
            for (int r = 0; r < 4; r++) bb[r] = b_mask[cs * 128 + c0 + r];
#pragma unroll
            for (int r = 0; r < 4; r++)
#pragma unroll
                for (int nf = 0; nf < 4; nf++)
                    Os[c0 + r][nf * 16 + l16] = acc[mf][nf][r] + bb[r];
        }
        __syncthreads();

        // vectorized epilogue: out = Os + x (float4; 256B contiguous per c-row)
        const float* xp = x + (size_t)b * CC * NN + (size_t)cs * 128 * NN + nb;
        float* op = out + (size_t)b * CC * NN + (size_t)cs * 128 * NN + nb;
#pragma unroll
        for (int i = 0; i < 8; i++) {
            int idx = t + 256 * i;        // 0..2047
            int c = idx >> 4, nq = (idx & 15) * 4;
            float4 osv = *(const float4*)&Os[c][nq];
            float4 xv = *(const float4*)(xp + (size_t)c * NN + nq);
            float4 ov;
            ov.x = osv.x + xv.x; ov.y = osv.y + xv.y;
            ov.z = osv.z + xv.z; ov.w = osv.w + xv.w;
            *(float4*)(op + (size_t)c * NN + nq) = ov;
        }
    }
}

extern "C" void kernel_launch(void* const* d_in, const int* in_sizes, int n_in,
                              void* d_out, int out_size, void* d_ws, size_t ws_size,
                              hipStream_t stream) {
    const float* x       = (const float*)d_in[0];
    const float* w_phi   = (const float*)d_in[1];
    const float* b_phi   = (const float*)d_in[2];
    const float* w_theta = (const float*)d_in[3];
    const float* b_theta = (const float*)d_in[4];
    const float* w_g     = (const float*)d_in[5];
    const float* b_g     = (const float*)d_in[6];
    const float* w_mask  = (const float*)d_in[7];
    const float* b_mask  = (const float*)d_in[8];
    float* out = (float*)d_out;

    // ws (48 MiB): [0,16M): Opart (2*8*4096*128 bf16 = 16 MiB)
    //              [16,24M): Q | [24,32M): K | [32,40M): Vt | [40M+): lsums (256 KiB)
    char* ws = (char*)d_ws;
    unsigned short* opart = (unsigned short*)(ws);
    unsigned short* qw    = (unsigned short*)(ws + ((size_t)16 << 20));
    unsigned short* kw    = (unsigned short*)(ws + ((size_t)24 << 20));
    unsigned short* vtw   = (unsigned short*)(ws + ((size_t)32 << 20));
    float*          lsums = (float*)(ws + ((size_t)40 << 20));

    k_proj<<<dim3(NN / 128, BB), 512, 0, stream>>>(x, w_phi, b_phi, w_theta, b_theta,
                                                   w_g, b_g, qw, kw, vtw);
    k_flash<<<dim3(1024, 1, 1), 128, 0, stream>>>(qw, kw, vtw, opart, lsums);
    k_maskout<<<dim3(NN / 64, BB), 256, 0, stream>>>(opart, lsums, w_mask, b_mask, x, out);
}

// Round 8
// 222.892 us; speedup vs baseline: 1.0690x; 1.0489x over previous
//
#include <hip/hip_runtime.h>

#define BB 8
#define CC 256
#define DD 128
#define NN 4096

#define LOG2E 1.44269504f
#define MSHIFT 32.0f  // fixed softmax shift (base-2 domain); |S*log2e| << 32 always

typedef __attribute__((ext_vector_type(8))) short short8;
typedef __attribute__((ext_vector_type(4))) short short4v;
typedef __attribute__((ext_vector_type(4))) float f32x4;
typedef __attribute__((ext_vector_type(16))) float f32x16;
typedef __attribute__((ext_vector_type(4))) unsigned int u32x4;

static __device__ __forceinline__ unsigned short f2bf(float f) {
    unsigned u = __builtin_bit_cast(unsigned, f);
    u += 0x7FFFu + ((u >> 16) & 1u);
    return (unsigned short)(u >> 16);
}
static __device__ __forceinline__ float bf2f(unsigned short h) {
    unsigned u = ((unsigned)h) << 16;
    return __builtin_bit_cast(float, u);
}
static __device__ __forceinline__ short8 pack8(float4 a, float4 b) {
    short8 r;
    r[0] = (short)f2bf(a.x); r[1] = (short)f2bf(a.y);
    r[2] = (short)f2bf(a.z); r[3] = (short)f2bf(a.w);
    r[4] = (short)f2bf(b.x); r[5] = (short)f2bf(b.y);
    r[6] = (short)f2bf(b.z); r[7] = (short)f2bf(b.w);
    return r;
}
// packed f32x2 -> bf16x2 (RNE); element 0 in low 16 bits
static __device__ __forceinline__ unsigned cvtpk_bf16(float lo, float hi) {
    unsigned r;
    asm("v_cvt_pk_bf16_f32 %0, %1, %2" : "=v"(r) : "v"(lo), "v"(hi));
    return r;
}
// swap upper 32 lanes of a with lower 32 lanes of b (T12 primitive)
static __device__ __forceinline__ void pl32swap(unsigned &a, unsigned &b) {
#if __has_builtin(__builtin_amdgcn_permlane32_swap)
    auto r = __builtin_amdgcn_permlane32_swap((int)a, (int)b, false, false);
    a = (unsigned)r[0]; b = (unsigned)r[1];
#else
    asm("v_permlane32_swap_b32 %0, %1" : "+v"(a), "+v"(b));
#endif
}
// async global->LDS DMA, 16 B/lane: LDS dest = wave-uniform base + lane*16 (m97/m104)
static __device__ __forceinline__ void gll16(const void* g, void* l) {
    __builtin_amdgcn_global_load_lds(
        (const __attribute__((address_space(1))) unsigned int*)g,
        (__attribute__((address_space(3))) unsigned int*)l, 16, 0, 0);
}
// counted VMEM wait (T4): literal-immediate variants; memory clobber pins mem ops
#define VMWAIT(N) asm volatile("s_waitcnt vmcnt(" #N ")" ::: "memory")

// ---------------- kernel 2: FUSED projections (x read ONCE; 3 MFMAs per B-frag) -------
// grid (NN/128, BB) = 256 blocks, block 512 = 8 waves; wave owns d-range (wave&3)*32,
// n-range (wave>>2)*64. Per kc chunk: stage x^T [128n][64c] bf16 into LDS (lane-contiguous
// fp32 reads, col swizzle (c + 8*(n>>4)) & 63), then accumulate theta/phi/g together.
// Outputs: Q=theta*log2e [n][d], K=phi [n][d], Vt=g [d][n]. Replaces 3 passes over x.
__global__ __launch_bounds__(512, 2) void k_proj(
        const float* __restrict__ x,
        const float* __restrict__ w_phi, const float* __restrict__ b_phi,
        const float* __restrict__ w_theta, const float* __restrict__ b_theta,
        const float* __restrict__ w_g, const float* __restrict__ b_g,
        unsigned short* __restrict__ qws, unsigned short* __restrict__ kws,
        unsigned short* __restrict__ vtws) {
    __shared__ __align__(16) unsigned short xs[128][72];     // staged x^T chunk (18432 B)
    __shared__ __align__(16) unsigned short rp[128][136];    // repack buffer (34816 B)
    int nb = blockIdx.x * 128, b = blockIdx.y;
    int t = threadIdx.x, lane = t & 63, wave = t >> 6;
    int l16 = lane & 15, l4 = lane >> 4;
    int wd = wave & 3, wn = wave >> 2;  // d-range wd*32, n-range wn*64

    f32x4 a_th[2][4], a_ph[2][4], a_g[2][4];
#pragma unroll
    for (int mf = 0; mf < 2; mf++)
#pragma unroll
        for (int nf = 0; nf < 4; nf++)
#pragma unroll
            for (int e = 0; e < 4; e++) { a_th[mf][nf][e] = 0.f; a_ph[mf][nf][e] = 0.f; a_g[mf][nf][e] = 0.f; }

    const float* xpb = x + (size_t)b * CC * NN;  // [c][n]

    for (int kc = 0; kc < 4; kc++) {
        int c0k = kc * 64;
        __syncthreads();
        {   // stage 64c x 128n: 2048 float4, lane-contiguous (1 KB/wave-instr)
            float4 xv[4];
#pragma unroll
            for (int j = 0; j < 4; j++) {
                int idx = t + 512 * j;
                int cr = idx >> 5, pos = idx & 31;
                xv[j] = *(const float4*)(xpb + (size_t)(c0k + cr) * NN + nb + pos * 4);
            }
#pragma unroll
            for (int j = 0; j < 4; j++) {
                int idx = t + 512 * j;
                int cr = idx >> 5, pos = idx & 31;
                int col = (cr + 8 * (pos >> 2)) & 63;
                xs[pos * 4 + 0][col] = f2bf(xv[j].x);
                xs[pos * 4 + 1][col] = f2bf(xv[j].y);
                xs[pos * 4 + 2][col] = f2bf(xv[j].z);
                xs[pos * 4 + 3][col] = f2bf(xv[j].w);
            }
        }
        __syncthreads();
        // weight A-frags for this c-chunk (L2-resident after first block)
        short8 af_t[2][2], af_p[2][2], af_g[2][2];  // [mf][ic]
#pragma unroll
        for (int mf = 0; mf < 2; mf++)
#pragma unroll
            for (int ic = 0; ic < 2; ic++) {
                int d = wd * 32 + mf * 16 + l16;
                int co = c0k + ic * 32 + l4 * 8;
                const float* wpt = w_theta + d * CC + co;
                const float* wpp = w_phi   + d * CC + co;
                const float* wpg = w_g     + d * CC + co;
                af_t[mf][ic] = pack8(*(const float4*)wpt, *(const float4*)(wpt + 4));
                af_p[mf][ic] = pack8(*(const float4*)wpp, *(const float4*)(wpp + 4));
                af_g[mf][ic] = pack8(*(const float4*)wpg, *(const float4*)(wpg + 4));
            }
#pragma unroll
        for (int nf = 0; nf < 4; nf++)
#pragma unroll
            for (int ic = 0; ic < 2; ic++) {
                int ncol = (ic * 32 + l4 * 8 + 8 * (wn * 4 + nf)) & 63;
                short8 bfr = *(const short8*)&xs[wn * 64 + nf * 16 + l16][ncol];
                a_th[0][nf] = __builtin_amdgcn_mfma_f32_16x16x32_bf16(af_t[0][ic], bfr, a_th[0][nf], 0, 0, 0);
                a_th[1][nf] = __builtin_amdgcn_mfma_f32_16x16x32_bf16(af_t[1][ic], bfr, a_th[1][nf], 0, 0, 0);
                a_ph[0][nf] = __builtin_amdgcn_mfma_f32_16x16x32_bf16(af_p[0][ic], bfr, a_ph[0][nf], 0, 0, 0);
                a_ph[1][nf] = __builtin_amdgcn_mfma_f32_16x16x32_bf16(af_p[1][ic], bfr, a_ph[1][nf], 0, 0, 0);
                a_g[0][nf]  = __builtin_amdgcn_mfma_f32_16x16x32_bf16(af_g[0][ic], bfr, a_g[0][nf], 0, 0, 0);
                a_g[1][nf]  = __builtin_amdgcn_mfma_f32_16x16x32_bf16(af_g[1][ic], bfr, a_g[1][nf], 0, 0, 0);
            }
    }
    // acc C-layout: col(l16) = n-within-frag, row(l4*4+r) = d-within-frag
    __syncthreads();  // xs reads done (rp disjoint, but keep phases clean)

    // ---- Q = theta * log2e, [n][d] ----
#pragma unroll
    for (int mf = 0; mf < 2; mf++) {
        int d0 = wd * 32 + mf * 16 + l4 * 4;
        float bb[4];
#pragma unroll
        for (int r = 0; r < 4; r++) bb[r] = b_theta[d0 + r];
#pragma unroll
        for (int nf = 0; nf < 4; nf++) {
            short4v pk;
#pragma unroll
            for (int r = 0; r < 4; r++) pk[r] = (short)f2bf((a_th[mf][nf][r] + bb[r]) * LOG2E);
            *(short4v*)&rp[wn * 64 + nf * 16 + l16][d0] = pk;
        }
    }
    __syncthreads();
    {
        unsigned short* outp = qws + (size_t)b * NN * DD;
#pragma unroll
        for (int i = 0; i < 4; i++) {
            int idx = t + 512 * i;
            int n = idx >> 4, dd = (idx & 15) * 8;
            *(short8*)(outp + (size_t)(nb + n) * DD + dd) = *(const short8*)&rp[n][dd];
        }
    }
    __syncthreads();

    // ---- K = phi, [n][d] ----
#pragma unroll
    for (int mf = 0; mf < 2; mf++) {
        int d0 = wd * 32 + mf * 16 + l4 * 4;
        float bb[4];
#pragma unroll
        for (int r = 0; r < 4; r++) bb[r] = b_phi[d0 + r];
#pragma unroll
        for (int nf = 0; nf < 4; nf++) {
            short4v pk;
#pragma unroll
            for (int r = 0; r < 4; r++) pk[r] = (short)f2bf(a_ph[mf][nf][r] + bb[r]);
            *(short4v*)&rp[wn * 64 + nf * 16 + l16][d0] = pk;
        }
    }
    __syncthreads();
    {
        unsigned short* outp = kws + (size_t)b * NN * DD;
#pragma unroll
        for (int i = 0; i < 4; i++) {
            int idx = t + 512 * i;
            int n = idx >> 4, dd = (idx & 15) * 8;
            *(short8*)(outp + (size_t)(nb + n) * DD + dd) = *(const short8*)&rp[n][dd];
        }
    }
    __syncthreads();

    // ---- Vt = g, [d][n] ----
#pragma unroll
    for (int mf = 0; mf < 2; mf++) {
        int drow = wd * 32 + mf * 16 + l4 * 4;
        float bb[4];
#pragma unroll
        for (int r = 0; r < 4; r++) bb[r] = b_g[drow + r];
#pragma unroll
        for (int nf = 0; nf < 4; nf++)
#pragma unroll
            for (int r = 0; r < 4; r++)
                rp[drow + r][wn * 64 + nf * 16 + l16] = f2bf(a_g[mf][nf][r] + bb[r]);
    }
    __syncthreads();
    {
        unsigned short* outp = vtws + (size_t)b * DD * NN;
#pragma unroll
        for (int i = 0; i < 4; i++) {
            int idx = t + 512 * i;
            int d = idx >> 4, n0s = (idx & 15) * 8;
            *(short8*)(outp + (size_t)d * NN + nb + n0s) = *(const short8*)&rp[d][n0s];
        }
    }
}

// ---------------- kernel 3: flash attention — ring-4 DMA, counted vmcnt (T4), no drain ----
// r7-verified math/DMA-swizzle; sync structure replaced: raw s_barrier + counted
// s_waitcnt vmcnt(N) (never 0 in main loop) with a 4-buffer LDS ring and depth-2
// prefetch (iter t issues DMA(t+2), waits vmcnt(8) -> tile t landed, barrier, compute).
// Race-freedom (barrier skew <= 1 iter): concurrent {write t+2, compute t, other-wave
// compute t-1, other-wave write t+1} touch buffers (t+2, t, t-1, t+1) mod 4 - pairwise
// distinct. Blocks = 256 thr / 4 waves, q-tile 128 -> grid 512 = exactly 2 blocks/CU
// (8 waves/CU, same TLP as r7 - isolates the drain-removal variable). KVBLK=32, NIT=64.
__global__ __launch_bounds__(256, 2) void k_flash(
        const unsigned short* __restrict__ q, const unsigned short* __restrict__ kk,
        const unsigned short* __restrict__ vt, unsigned short* __restrict__ opart,
        float* __restrict__ lsums) {
    __shared__ __align__(16) unsigned char smem[65536];
    // buf i at smem + i*16384: K (32 rows x 256 B) at +0, V (128 rows x 64 B) at +8192

    int bid = blockIdx.x;
    int b   = bid & 7;           // batch -> XCD (round-robin dispatch): K/V L2-resident
    int rem = bid >> 3;          // 0..63
    int ks  = rem >> 5;          // 0..1
    int qt  = rem & 31;          // 0..31
    int qb  = qt * 128;

    int t = threadIdx.x, lane = t & 63, wave = t >> 6;  // wave 0..3
    int l31 = lane & 31, hi = lane >> 5;

    const unsigned short* qp = q  + (size_t)b * NN * DD;
    const unsigned short* kp = kk + (size_t)b * NN * DD;
    const unsigned short* vp = vt + (size_t)b * DD * NN;

    // Q fragments (B-operand of swapped QK^T): lane holds Q[qb+w*32+l31][kc*16+hi*8+e]
    short8 qreg[8];
    {
        int qrow = qb + wave * 32 + l31;
#pragma unroll
        for (int kc = 0; kc < 8; kc++)
            qreg[kc] = *(const short8*)(qp + (size_t)qrow * DD + kc * 16 + hi * 8);
    }

    // per-lane DMA source offsets (elements): wave stages 2 K-segs + 2 V-segs (1024 B each).
    // K seg s covers rows 4s..4s+3 (lane>>4 = row-in-seg, lane&15 = dest chunk c');
    // src chunk = c' ^ (row&7)  ->  LDS[row][c'] = G[row][c'^(row&7)]  (swizzled layout).
    // V seg s covers d-rows 16s..16s+15; src chunk = c' ^ ((row^(row>>2))&3).
    int koff[2], voff[2];
#pragma unroll
    for (int j = 0; j < 2; j++) {
        int seg = wave * 2 + j;
        int krow = seg * 4 + (lane >> 4);
        koff[j] = krow * DD + (((lane & 15) ^ (krow & 7)) << 3);
        int vrow = seg * 16 + (lane >> 2);
        voff[j] = vrow * NN + (((lane & 3) ^ ((vrow ^ (vrow >> 2)) & 3)) << 3);
    }

    f32x16 o[4];
#pragma unroll
    for (int df = 0; df < 4; df++)
#pragma unroll
        for (int e = 0; e < 16; e++) o[df][e] = 0.f;
    float lsum0 = 0.f, lsum1 = 0.f;

    int kbase = ks * (NN / 2);
    const int NIT = (NN / 2) / 32;  // 64

    // prologue: issue DMA for tiles 0 and 1 (no waits; 8 ops/wave in flight)
#pragma unroll
    for (int pt = 0; pt < 2; pt++) {
        int mb = kbase + pt * 32;
        char* Kb = (char*)smem + pt * 16384;
#pragma unroll
        for (int j = 0; j < 2; j++) {
            int seg = wave * 2 + j;
            gll16(kp + (size_t)mb * DD + koff[j], Kb + seg * 1024);
            gll16(vp + mb + voff[j], Kb + 8192 + seg * 1024);
        }
    }

    for (int it = 0; it < NIT; ++it) {
        char* Kb = (char*)smem + (it & 3) * 16384;
        char* Vb = Kb + 8192;

        // T4: issue DMA(t+2) into ring slot, then counted wait (tile t done, t+1/t+2 fly)
        if (it + 2 < NIT) {
            int mb2 = kbase + (it + 2) * 32;
            char* KbW = (char*)smem + ((it + 2) & 3) * 16384;
#pragma unroll
            for (int j = 0; j < 2; j++) {
                int seg = wave * 2 + j;
                gll16(kp + (size_t)mb2 * DD + koff[j], KbW + seg * 1024);
                gll16(vp + mb2 + voff[j], KbW + 8192 + seg * 1024);
            }
            VMWAIT(8);
        } else if (it + 1 < NIT) {
            VMWAIT(4);
        } else {
            VMWAIT(0);
        }
        __builtin_amdgcn_s_barrier();       // raw barrier: NO vmcnt drain
        asm volatile("" ::: "memory");      // pin post-barrier LDS reads below barrier

        // S^T = K . Q^T - 32 (two interleaved accumulators -> MFMA dep-distance 2)
        f32x16 sA, sB;
#pragma unroll
        for (int e = 0; e < 16; e++) { sA[e] = -MSHIFT; sB[e] = 0.f; }
        __builtin_amdgcn_s_setprio(1);
#pragma unroll
        for (int kc = 0; kc < 8; kc += 2) {
            short8 a0 = *(const short8*)(Kb + l31 * 256 + ((((kc << 1) | hi) ^ (l31 & 7)) << 4));
            short8 a1 = *(const short8*)(Kb + l31 * 256 + (((((kc + 1) << 1) | hi) ^ (l31 & 7)) << 4));
            sA = __builtin_amdgcn_mfma_f32_32x32x16_bf16(a0, qreg[kc], sA, 0, 0, 0);
            sB = __builtin_amdgcn_mfma_f32_32x32x16_bf16(a1, qreg[kc + 1], sB, 0, 0, 0);
        }
        __builtin_amdgcn_s_setprio(0);

        // p = exp2(s'); lane-local row partials; PV A-frags in-register (T12)
        u32x4 pa[2];
        {
            float p[16];
#pragma unroll
            for (int r = 0; r < 16; r++) {
                p[r] = __builtin_exp2f(sA[r] + sB[r]);
                if (r & 1) lsum1 += p[r]; else lsum0 += p[r];
            }
#pragma unroll
            for (int h = 0; h < 2; h++) {
                unsigned a0 = cvtpk_bf16(p[8 * h + 0], p[8 * h + 1]);
                unsigned a1 = cvtpk_bf16(p[8 * h + 2], p[8 * h + 3]);
                unsigned b0 = cvtpk_bf16(p[8 * h + 4], p[8 * h + 5]);
                unsigned b1 = cvtpk_bf16(p[8 * h + 6], p[8 * h + 7]);
                pl32swap(a0, b0);
                pl32swap(a1, b1);
                u32x4 v; v[0] = a0; v[1] = a1; v[2] = b0; v[3] = b1;
                pa[h] = v;
            }
        }

        // O += P V  (V^T stored -> B-frag is a direct contiguous ds_read_b128)
        __builtin_amdgcn_s_setprio(1);
#pragma unroll
        for (int df = 0; df < 4; df++) {
            int row = df * 32 + l31;
            int sw = (row ^ (row >> 2)) & 3;
#pragma unroll
            for (int c = 0; c < 2; c++) {
                short8 vb = *(const short8*)(Vb + row * 64 + ((((c << 1) | hi) ^ sw) << 4));
                o[df] = __builtin_amdgcn_mfma_f32_32x32x16_bf16(
                    __builtin_bit_cast(short8, pa[c]), vb, o[df], 0, 0, 0);
            }
        }
        __builtin_amdgcn_s_setprio(0);
        // no end-of-iter barrier: next iter's wait+barrier provides the ordering
    }

    // ---- epilogue: row-sums + staged coalesced O-partial store ----
    {
        float lsum = lsum0 + lsum1;
        float tot = lsum + __shfl_xor(lsum, 32);
        if (lane < 32)
            lsums[((size_t)ks * BB + b) * NN + qb + wave * 32 + l31] = tot;
    }
    __syncthreads();  // full drain once: all waves done with ring bufs before Ox overlay
    unsigned short (*Ox)[136] = (unsigned short (*)[136])smem;  // 128 x 136 (34816 B)
#pragma unroll
    for (int df = 0; df < 4; df++)
#pragma unroll
        for (int r = 0; r < 16; r++) {
            int qr = (r & 3) + 8 * (r >> 2) + 4 * hi;
            Ox[wave * 32 + qr][df * 32 + l31] = f2bf(o[df][r]);
        }
    __syncthreads();
    unsigned short* op = opart + (((size_t)ks * BB + b) * NN + qb) * DD;
#pragma unroll
    for (int i = 0; i < 8; i++) {
        int idx = t + 256 * i;  // 0..2047
        int nr = idx >> 4, c0 = (idx & 15) * 8;
        *(short8*)(op + (size_t)nr * DD + c0) = *(const short8*)&Ox[nr][c0];
    }
}

// ---------------- kernel 4: combine partials + out = w_mask . y^T + b_mask + x ----------------
// grid (NN/64, BB), block 256; BOTH c-halves per block (opart/Ys staged once, cs loop).
// Ys and Os are disjoint LDS regions (52.5 KB total) -> 2 blocks/CU.
__global__ __launch_bounds__(256) void k_maskout(
        const unsigned short* __restrict__ opart, const float* __restrict__ lsums,
        const float* __restrict__ w_mask, const float* __restrict__ b_mask,
        const float* __restrict__ x, float* __restrict__ out) {
    __shared__ __align__(16) unsigned char pool[52480];
    unsigned short (*Ys)[136] = (unsigned short (*)[136])pool;   // 64x136x2B = 17408
    float (*Os)[68] = (float (*)[68])(pool + 17408);             // 128x68x4B = 34816
    float* invl = (float*)(pool + 52224);                        // 256 B
    int nb = blockIdx.x * 64, b = blockIdx.y;
    int t = threadIdx.x, lane = t & 63, wave = t >> 6;
    int l16 = lane & 15, l4 = lane >> 4;

    const unsigned short* o0 = opart + ((size_t)b * NN + nb) * DD;
    const unsigned short* o1 = opart + (((size_t)BB + b) * NN + nb) * DD;
    if (t < 64) {
        float ls0 = lsums[(size_t)b * NN + nb + t];
        float ls1 = lsums[((size_t)BB + b) * NN + nb + t];
        invl[t] = 1.0f / (ls0 + ls1);
    }
    __syncthreads();
#pragma unroll
    for (int i = 0; i < 4; i++) {  // combine the 2 key-split partials while staging y
        int idx = t + 256 * i;
        int nr = idx >> 4, d0 = (idx & 15) * 8;
        short8 a = *(const short8*)(o0 + (size_t)nr * DD + d0);
        short8 c = *(const short8*)(o1 + (size_t)nr * DD + d0);
        float inv = invl[nr];
        short8 yv;
#pragma unroll
        for (int j = 0; j < 8; j++)
            yv[j] = (short)f2bf((bf2f((unsigned short)a[j]) + bf2f((unsigned short)c[j])) * inv);
        *(short8*)&Ys[nr][d0] = yv;
    }
    __syncthreads();

    for (int cs = 0; cs < 2; cs++) {
        f32x4 acc[2][4];
#pragma unroll
        for (int mf = 0; mf < 2; mf++)
#pragma unroll
            for (int nf = 0; nf < 4; nf++)
#pragma unroll
                for (int e = 0; e < 4; e++) acc[mf][nf][e] = 0.f;

#pragma unroll
        for (int kc = 0; kc < 4; kc++) {
            int d0 = kc * 32 + l4 * 8;
            short8 af[2];
#pragma unroll
            for (int mf = 0; mf < 2; mf++) {
                int c = cs * 128 + wave * 32 + mf * 16 + l16;
                const float* wp = w_mask + c * DD + d0;
                af[mf] = pack8(*(const float4*)wp, *(const float4*)(wp + 4));
            }
#pragma unroll
            for (int nf = 0; nf < 4; nf++) {
                short8 bfr = *(const short8*)&Ys[nf * 16 + l16][d0];
#pragma unroll
                for (int mf = 0; mf < 2; mf++)
                    acc[mf][nf] = __builtin_amdgcn_mfma_f32_16x16x32_bf16(af[mf], bfr, acc[mf][nf], 0, 0, 0);
            }
        }
        __syncthreads();  // cs=1: previous epilogue's Os reads done (no-op cost at cs=0)

        // stage acc + bias into Os[128][68] fp32
#pragma unroll
        for (int mf = 0; mf < 2; mf++) {
            int c0 = wave * 32 + mf * 16 + l4 * 4;  // local c 0..127
            float bb[4];
#pragma unroll
            for (int r = 0; r < 4; r++) bb[r] = b_mask[cs * 128 + c0 + r];
#pragma unroll
            for (int r = 0; r < 4; r++)
#pragma unroll
                for (int nf = 0; nf < 4; nf++)
                    Os[c0 + r][nf * 16 + l16] = acc[mf][nf][r] + bb[r];
        }
        __syncthreads();

        // vectorized epilogue: out = Os + x (float4; 256B contiguous per c-row)
        const float* xp = x + (size_t)b * CC * NN + (size_t)cs * 128 * NN + nb;
        float* op = out + (size_t)b * CC * NN + (size_t)cs * 128 * NN + nb;
#pragma unroll
        for (int i = 0; i < 8; i++) {
            int idx = t + 256 * i;        // 0..2047
            int c = idx >> 4, nq = (idx & 15) * 4;
            float4 osv = *(const float4*)&Os[c][nq];
            float4 xv = *(const float4*)(xp + (size_t)c * NN + nq);
            float4 ov;
            ov.x = osv.x + xv.x; ov.y = osv.y + xv.y;
            ov.z = osv.z + xv.z; ov.w = osv.w + xv.w;
            *(float4*)(op + (size_t)c * NN + nq) = ov;
        }
    }
}

extern "C" void kernel_launch(void* const* d_in, const int* in_sizes, int n_in,
                              void* d_out, int out_size, void* d_ws, size_t ws_size,
                              hipStream_t stream) {
    const float* x       = (const float*)d_in[0];
    const float* w_phi   = (const float*)d_in[1];
    const float* b_phi   = (const float*)d_in[2];
    const float* w_theta = (const float*)d_in[3];
    const float* b_theta = (const float*)d_in[4];
    const float* w_g     = (const float*)d_in[5];
    const float* b_g     = (const float*)d_in[6];
    const float* w_mask  = (const float*)d_in[7];
    const float* b_mask  = (const float*)d_in[8];
    float* out = (float*)d_out;

    // ws (48 MiB): [0,16M): Opart (2*8*4096*128 bf16 = 16 MiB)
    //              [16,24M): Q | [24,32M): K | [32,40M): Vt | [40M+): lsums (256 KiB)
    char* ws = (char*)d_ws;
    unsigned short* opart = (unsigned short*)(ws);
    unsigned short* qw    = (unsigned short*)(ws + ((size_t)16 << 20));
    unsigned short* kw    = (unsigned short*)(ws + ((size_t)24 << 20));
    unsigned short* vtw   = (unsigned short*)(ws + ((size_t)32 << 20));
    float*          lsums = (float*)(ws + ((size_t)40 << 20));

    k_proj<<<dim3(NN / 128, BB), 512, 0, stream>>>(x, w_phi, b_phi, w_theta, b_theta,
                                                   w_g, b_g, qw, kw, vtw);
    k_flash<<<dim3(512, 1, 1), 256, 0, stream>>>(qw, kw, vtw, opart, lsums);
    k_maskout<<<dim3(NN / 64, BB), 256, 0, stream>>>(opart, lsums, w_mask, b_mask, x, out);
}

// Round 9
// 220.552 us; speedup vs baseline: 1.0804x; 1.0106x over previous
//
#include <hip/hip_runtime.h>

#define BB 8
#define CC 256
#define DD 128
#define NN 4096

#define LOG2E 1.44269504f
#define MSHIFT 32.0f  // fixed softmax shift (base-2 domain); |S*log2e| << 32 always

typedef __attribute__((ext_vector_type(8))) short short8;
typedef __attribute__((ext_vector_type(4))) short short4v;
typedef __attribute__((ext_vector_type(4))) float f32x4;
typedef __attribute__((ext_vector_type(16))) float f32x16;
typedef __attribute__((ext_vector_type(4))) unsigned int u32x4;

static __device__ __forceinline__ unsigned short f2bf(float f) {
    unsigned u = __builtin_bit_cast(unsigned, f);
    u += 0x7FFFu + ((u >> 16) & 1u);
    return (unsigned short)(u >> 16);
}
static __device__ __forceinline__ float bf2f(unsigned short h) {
    unsigned u = ((unsigned)h) << 16;
    return __builtin_bit_cast(float, u);
}
static __device__ __forceinline__ short8 pack8(float4 a, float4 b) {
    short8 r;
    r[0] = (short)f2bf(a.x); r[1] = (short)f2bf(a.y);
    r[2] = (short)f2bf(a.z); r[3] = (short)f2bf(a.w);
    r[4] = (short)f2bf(b.x); r[5] = (short)f2bf(b.y);
    r[6] = (short)f2bf(b.z); r[7] = (short)f2bf(b.w);
    return r;
}
// packed f32x2 -> bf16x2 (RNE); element 0 in low 16 bits
static __device__ __forceinline__ unsigned cvtpk_bf16(float lo, float hi) {
    unsigned r;
    asm("v_cvt_pk_bf16_f32 %0, %1, %2" : "=v"(r) : "v"(lo), "v"(hi));
    return r;
}
// swap upper 32 lanes of a with lower 32 lanes of b (T12 primitive)
static __device__ __forceinline__ void pl32swap(unsigned &a, unsigned &b) {
#if __has_builtin(__builtin_amdgcn_permlane32_swap)
    auto r = __builtin_amdgcn_permlane32_swap((int)a, (int)b, false, false);
    a = (unsigned)r[0]; b = (unsigned)r[1];
#else
    asm("v_permlane32_swap_b32 %0, %1" : "+v"(a), "+v"(b));
#endif
}
// async global->LDS DMA, 16 B/lane: LDS dest = wave-uniform base + lane*16 (m97/m104)
static __device__ __forceinline__ void gll16(const void* g, void* l) {
    __builtin_amdgcn_global_load_lds(
        (const __attribute__((address_space(1))) unsigned int*)g,
        (__attribute__((address_space(3))) unsigned int*)l, 16, 0, 0);
}
// counted VMEM wait (T4): literal-immediate variants; memory clobber pins mem ops
#define VMWAIT(N) asm volatile("s_waitcnt vmcnt(" #N ")" ::: "memory")

// ---------------- kernel 2: FUSED projections (x read ONCE; 3 MFMAs per B-frag) -------
// grid (NN/128, BB) = 256 blocks, block 512 = 8 waves; wave owns d-range (wave&3)*32,
// n-range (wave>>2)*64. Per kc chunk: stage x^T [128n][64c] bf16 into LDS (lane-contiguous
// fp32 reads, col swizzle (c + 8*(n>>4)) & 63), then accumulate theta/phi/g together.
// Outputs: Q=theta*log2e [n][d], K=phi [n][d], Vt=g [d][n]. Replaces 3 passes over x.
__global__ __launch_bounds__(512, 2) void k_proj(
        const float* __restrict__ x,
        const float* __restrict__ w_phi, const float* __restrict__ b_phi,
        const float* __restrict__ w_theta, const float* __restrict__ b_theta,
        const float* __restrict__ w_g, const float* __restrict__ b_g,
        unsigned short* __restrict__ qws, unsigned short* __restrict__ kws,
        unsigned short* __restrict__ vtws) {
    __shared__ __align__(16) unsigned short xs[128][72];     // staged x^T chunk (18432 B)
    __shared__ __align__(16) unsigned short rp[128][136];    // repack buffer (34816 B)
    int nb = blockIdx.x * 128, b = blockIdx.y;
    int t = threadIdx.x, lane = t & 63, wave = t >> 6;
    int l16 = lane & 15, l4 = lane >> 4;
    int wd = wave & 3, wn = wave >> 2;  // d-range wd*32, n-range wn*64

    f32x4 a_th[2][4], a_ph[2][4], a_g[2][4];
#pragma unroll
    for (int mf = 0; mf < 2; mf++)
#pragma unroll
        for (int nf = 0; nf < 4; nf++)
#pragma unroll
            for (int e = 0; e < 4; e++) { a_th[mf][nf][e] = 0.f; a_ph[mf][nf][e] = 0.f; a_g[mf][nf][e] = 0.f; }

    const float* xpb = x + (size_t)b * CC * NN;  // [c][n]

    for (int kc = 0; kc < 4; kc++) {
        int c0k = kc * 64;
        __syncthreads();
        {   // stage 64c x 128n: 2048 float4, lane-contiguous (1 KB/wave-instr)
            float4 xv[4];
#pragma unroll
            for (int j = 0; j < 4; j++) {
                int idx = t + 512 * j;
                int cr = idx >> 5, pos = idx & 31;
                xv[j] = *(const float4*)(xpb + (size_t)(c0k + cr) * NN + nb + pos * 4);
            }
#pragma unroll
            for (int j = 0; j < 4; j++) {
                int idx = t + 512 * j;
                int cr = idx >> 5, pos = idx & 31;
                int col = (cr + 8 * (pos >> 2)) & 63;
                xs[pos * 4 + 0][col] = f2bf(xv[j].x);
                xs[pos * 4 + 1][col] = f2bf(xv[j].y);
                xs[pos * 4 + 2][col] = f2bf(xv[j].z);
                xs[pos * 4 + 3][col] = f2bf(xv[j].w);
            }
        }
        __syncthreads();
        // weight A-frags for this c-chunk (L2-resident after first block)
        short8 af_t[2][2], af_p[2][2], af_g[2][2];  // [mf][ic]
#pragma unroll
        for (int mf = 0; mf < 2; mf++)
#pragma unroll
            for (int ic = 0; ic < 2; ic++) {
                int d = wd * 32 + mf * 16 + l16;
                int co = c0k + ic * 32 + l4 * 8;
                const float* wpt = w_theta + d * CC + co;
                const float* wpp = w_phi   + d * CC + co;
                const float* wpg = w_g     + d * CC + co;
                af_t[mf][ic] = pack8(*(const float4*)wpt, *(const float4*)(wpt + 4));
                af_p[mf][ic] = pack8(*(const float4*)wpp, *(const float4*)(wpp + 4));
                af_g[mf][ic] = pack8(*(const float4*)wpg, *(const float4*)(wpg + 4));
            }
#pragma unroll
        for (int nf = 0; nf < 4; nf++)
#pragma unroll
            for (int ic = 0; ic < 2; ic++) {
                int ncol = (ic * 32 + l4 * 8 + 8 * (wn * 4 + nf)) & 63;
                short8 bfr = *(const short8*)&xs[wn * 64 + nf * 16 + l16][ncol];
                a_th[0][nf] = __builtin_amdgcn_mfma_f32_16x16x32_bf16(af_t[0][ic], bfr, a_th[0][nf], 0, 0, 0);
                a_th[1][nf] = __builtin_amdgcn_mfma_f32_16x16x32_bf16(af_t[1][ic], bfr, a_th[1][nf], 0, 0, 0);
                a_ph[0][nf] = __builtin_amdgcn_mfma_f32_16x16x32_bf16(af_p[0][ic], bfr, a_ph[0][nf], 0, 0, 0);
                a_ph[1][nf] = __builtin_amdgcn_mfma_f32_16x16x32_bf16(af_p[1][ic], bfr, a_ph[1][nf], 0, 0, 0);
                a_g[0][nf]  = __builtin_amdgcn_mfma_f32_16x16x32_bf16(af_g[0][ic], bfr, a_g[0][nf], 0, 0, 0);
                a_g[1][nf]  = __builtin_amdgcn_mfma_f32_16x16x32_bf16(af_g[1][ic], bfr, a_g[1][nf], 0, 0, 0);
            }
    }
    // acc C-layout: col(l16) = n-within-frag, row(l4*4+r) = d-within-frag
    __syncthreads();  // xs reads done (rp disjoint, but keep phases clean)

    // ---- Q = theta * log2e, [n][d] ----
#pragma unroll
    for (int mf = 0; mf < 2; mf++) {
        int d0 = wd * 32 + mf * 16 + l4 * 4;
        float bb[4];
#pragma unroll
        for (int r = 0; r < 4; r++) bb[r] = b_theta[d0 + r];
#pragma unroll
        for (int nf = 0; nf < 4; nf++) {
            short4v pk;
#pragma unroll
            for (int r = 0; r < 4; r++) pk[r] = (short)f2bf((a_th[mf][nf][r] + bb[r]) * LOG2E);
            *(short4v*)&rp[wn * 64 + nf * 16 + l16][d0] = pk;
        }
    }
    __syncthreads();
    {
        unsigned short* outp = qws + (size_t)b * NN * DD;
#pragma unroll
        for (int i = 0; i < 4; i++) {
            int idx = t + 512 * i;
            int n = idx >> 4, dd = (idx & 15) * 8;
            *(short8*)(outp + (size_t)(nb + n) * DD + dd) = *(const short8*)&rp[n][dd];
        }
    }
    __syncthreads();

    // ---- K = phi, [n][d] ----
#pragma unroll
    for (int mf = 0; mf < 2; mf++) {
        int d0 = wd * 32 + mf * 16 + l4 * 4;
        float bb[4];
#pragma unroll
        for (int r = 0; r < 4; r++) bb[r] = b_phi[d0 + r];
#pragma unroll
        for (int nf = 0; nf < 4; nf++) {
            short4v pk;
#pragma unroll
            for (int r = 0; r < 4; r++) pk[r] = (short)f2bf(a_ph[mf][nf][r] + bb[r]);
            *(short4v*)&rp[wn * 64 + nf * 16 + l16][d0] = pk;
        }
    }
    __syncthreads();
    {
        unsigned short* outp = kws + (size_t)b * NN * DD;
#pragma unroll
        for (int i = 0; i < 4; i++) {
            int idx = t + 512 * i;
            int n = idx >> 4, dd = (idx & 15) * 8;
            *(short8*)(outp + (size_t)(nb + n) * DD + dd) = *(const short8*)&rp[n][dd];
        }
    }
    __syncthreads();

    // ---- Vt = g, [d][n] ----
#pragma unroll
    for (int mf = 0; mf < 2; mf++) {
        int drow = wd * 32 + mf * 16 + l4 * 4;
        float bb[4];
#pragma unroll
        for (int r = 0; r < 4; r++) bb[r] = b_g[drow + r];
#pragma unroll
        for (int nf = 0; nf < 4; nf++)
#pragma unroll
            for (int r = 0; r < 4; r++)
                rp[drow + r][wn * 64 + nf * 16 + l16] = f2bf(a_g[mf][nf][r] + bb[r]);
    }
    __syncthreads();
    {
        unsigned short* outp = vtws + (size_t)b * DD * NN;
#pragma unroll
        for (int i = 0; i < 4; i++) {
            int idx = t + 512 * i;
            int d = idx >> 4, n0s = (idx & 15) * 8;
            *(short8*)(outp + (size_t)d * NN + nb + n0s) = *(const short8*)&rp[d][n0s];
        }
    }
}

// ---------------- kernel 3: flash attention — ring-4 DMA, counted vmcnt, lean VALU ------
// r8-verified sync structure (ring-4, depth-2 prefetch, raw barrier, counted vmcnt).
// This round: (1) single chained S-accumulator (MFMA C-forwarding is full-rate) — drops
// 16 v_add + 16 v_mov per wave-iter; (2) all LDS-read addresses precomputed as
// loop-invariant registers (V swizzle (row^(row>>2))&3 = (l31^(l31>>2))&3 is
// df-independent -> V reads are Vb + df*2048 + vvo[c]); (3) main loop unrolled x4 so
// ring bases are compile-time and fold into ds_read offset immediates.
// grid 512 = 8 b x 2 ks x 32 q-tiles (2 blocks/CU, 8 waves/CU). KVBLK=32, NIT=64.
__global__ __launch_bounds__(256, 2) void k_flash(
        const unsigned short* __restrict__ q, const unsigned short* __restrict__ kk,
        const unsigned short* __restrict__ vt, unsigned short* __restrict__ opart,
        float* __restrict__ lsums) {
    __shared__ __align__(16) unsigned char smem[65536];
    // buf i at smem + i*16384: K (32 rows x 256 B) at +0, V (128 rows x 64 B) at +8192

    int bid = blockIdx.x;
    int b   = bid & 7;           // batch -> XCD (round-robin dispatch): K/V L2-resident
    int rem = bid >> 3;          // 0..63
    int ks  = rem >> 5;          // 0..1
    int qt  = rem & 31;          // 0..31
    int qb  = qt * 128;

    int t = threadIdx.x, lane = t & 63, wave = t >> 6;  // wave 0..3
    int l31 = lane & 31, hi = lane >> 5;

    const unsigned short* qp = q  + (size_t)b * NN * DD;
    const unsigned short* kp = kk + (size_t)b * NN * DD;
    const unsigned short* vp = vt + (size_t)b * DD * NN;

    // Q fragments (B-operand of swapped QK^T): lane holds Q[qb+w*32+l31][kc*16+hi*8+e]
    short8 qreg[8];
    {
        int qrow = qb + wave * 32 + l31;
#pragma unroll
        for (int kc = 0; kc < 8; kc++)
            qreg[kc] = *(const short8*)(qp + (size_t)qrow * DD + kc * 16 + hi * 8);
    }

    // per-lane DMA source offsets (elements): wave stages 2 K-segs + 2 V-segs (1024 B each).
    // K seg s covers rows 4s..4s+3; src chunk = c' ^ (row&7) -> LDS[row][c'] = swizzled.
    // V seg s covers d-rows 16s..16s+15; src chunk = c' ^ ((row^(row>>2))&3).
    int koff[2], voff[2];
#pragma unroll
    for (int j = 0; j < 2; j++) {
        int seg = wave * 2 + j;
        int krow = seg * 4 + (lane >> 4);
        koff[j] = krow * DD + (((lane & 15) ^ (krow & 7)) << 3);
        int vrow = seg * 16 + (lane >> 2);
        voff[j] = vrow * NN + (((lane & 3) ^ ((vrow ^ (vrow >> 2)) & 3)) << 3);
    }

    // loop-invariant LDS READ byte-offsets (within a ring slot):
    // K: kvo[kc] = l31*256 + (((kc<<1|hi) ^ (l31&7)) << 4)
    // V: vvo[c]  = l31*64  + (((c<<1|hi) ^ ((l31^(l31>>2))&3)) << 4); read at +df*2048
    int kvo[8], vvo[2];
    {
        int e = l31 & 7;
#pragma unroll
        for (int kc = 0; kc < 8; kc++)
            kvo[kc] = l31 * 256 + ((((kc << 1) | hi) ^ e) << 4);
        int sw = (l31 ^ (l31 >> 2)) & 3;
#pragma unroll
        for (int c = 0; c < 2; c++)
            vvo[c] = l31 * 64 + ((((c << 1) | hi) ^ sw) << 4);
    }

    f32x16 o[4];
#pragma unroll
    for (int df = 0; df < 4; df++)
#pragma unroll
        for (int e = 0; e < 16; e++) o[df][e] = 0.f;
    float lsum0 = 0.f, lsum1 = 0.f;

    int kbase = ks * (NN / 2);
    const int NIT = (NN / 2) / 32;  // 64

    // prologue: issue DMA for tiles 0 and 1 (no waits; 8 ops/wave in flight)
#pragma unroll
    for (int pt = 0; pt < 2; pt++) {
        int mb = kbase + pt * 32;
        char* Kb = (char*)smem + pt * 16384;
#pragma unroll
        for (int j = 0; j < 2; j++) {
            int seg = wave * 2 + j;
            gll16(kp + (size_t)mb * DD + koff[j], Kb + seg * 1024);
            gll16(vp + mb + voff[j], Kb + 8192 + seg * 1024);
        }
    }

#pragma unroll 4
    for (int it = 0; it < NIT; ++it) {
        char* Kb = (char*)smem + (it & 3) * 16384;   // compile-time base under unroll-4
        char* Vb = Kb + 8192;

        // T4: issue DMA(t+2) into ring slot, then counted wait (tile t landed; t+1/t+2 fly)
        if (it + 2 < NIT) {
            int mb2 = kbase + (it + 2) * 32;
            char* KbW = (char*)smem + ((it + 2) & 3) * 16384;
#pragma unroll
            for (int j = 0; j < 2; j++) {
                int seg = wave * 2 + j;
                gll16(kp + (size_t)mb2 * DD + koff[j], KbW + seg * 1024);
                gll16(vp + mb2 + voff[j], KbW + 8192 + seg * 1024);
            }
            VMWAIT(8);
        } else if (it + 1 < NIT) {
            VMWAIT(4);
        } else {
            VMWAIT(0);
        }
        __builtin_amdgcn_s_barrier();       // raw barrier: NO vmcnt drain
        asm volatile("" ::: "memory");      // pin post-barrier LDS reads below barrier

        // S^T = K . Q^T - 32 : single chained accumulator (full-rate C-forwarding)
        f32x16 s;
#pragma unroll
        for (int e = 0; e < 16; e++) s[e] = -MSHIFT;
        __builtin_amdgcn_s_setprio(1);
#pragma unroll
        for (int kc = 0; kc < 8; kc++) {
            short8 a0 = *(const short8*)(Kb + kvo[kc]);
            s = __builtin_amdgcn_mfma_f32_32x32x16_bf16(a0, qreg[kc], s, 0, 0, 0);
        }
        __builtin_amdgcn_s_setprio(0);

        // p = exp2(s); lane-local row partials; PV A-frags in-register (T12)
        u32x4 pa[2];
        {
            float p[16];
#pragma unroll
            for (int r = 0; r < 16; r++) {
                p[r] = __builtin_exp2f(s[r]);
                if (r & 1) lsum1 += p[r]; else lsum0 += p[r];
            }
#pragma unroll
            for (int h = 0; h < 2; h++) {
                unsigned a0 = cvtpk_bf16(p[8 * h + 0], p[8 * h + 1]);
                unsigned a1 = cvtpk_bf16(p[8 * h + 2], p[8 * h + 3]);
                unsigned b0 = cvtpk_bf16(p[8 * h + 4], p[8 * h + 5]);
                unsigned b1 = cvtpk_bf16(p[8 * h + 6], p[8 * h + 7]);
                pl32swap(a0, b0);
                pl32swap(a1, b1);
                u32x4 v; v[0] = a0; v[1] = a1; v[2] = b0; v[3] = b1;
                pa[h] = v;
            }
        }

        // O += P V  (V^T stored -> B-frag is a direct contiguous ds_read_b128)
        __builtin_amdgcn_s_setprio(1);
#pragma unroll
        for (int df = 0; df < 4; df++) {
#pragma unroll
            for (int c = 0; c < 2; c++) {
                short8 vb = *(const short8*)(Vb + df * 2048 + vvo[c]);
                o[df] = __builtin_amdgcn_mfma_f32_32x32x16_bf16(
                    __builtin_bit_cast(short8, pa[c]), vb, o[df], 0, 0, 0);
            }
        }
        __builtin_amdgcn_s_setprio(0);
        // no end-of-iter barrier: next iter's wait+barrier provides the ordering
    }

    // ---- epilogue: row-sums + staged coalesced O-partial store ----
    {
        float lsum = lsum0 + lsum1;
        float tot = lsum + __shfl_xor(lsum, 32);
        if (lane < 32)
            lsums[((size_t)ks * BB + b) * NN + qb + wave * 32 + l31] = tot;
    }
    __syncthreads();  // full drain once: all waves done with ring bufs before Ox overlay
    unsigned short (*Ox)[136] = (unsigned short (*)[136])smem;  // 128 x 136 (34816 B)
#pragma unroll
    for (int df = 0; df < 4; df++)
#pragma unroll
        for (int r = 0; r < 16; r++) {
            int qr = (r & 3) + 8 * (r >> 2) + 4 * hi;
            Ox[wave * 32 + qr][df * 32 + l31] = f2bf(o[df][r]);
        }
    __syncthreads();
    unsigned short* op = opart + (((size_t)ks * BB + b) * NN + qb) * DD;
#pragma unroll
    for (int i = 0; i < 8; i++) {
        int idx = t + 256 * i;  // 0..2047
        int nr = idx >> 4, c0 = (idx & 15) * 8;
        *(short8*)(op + (size_t)nr * DD + c0) = *(const short8*)&Ox[nr][c0];
    }
}

// ---------------- kernel 4: combine partials + out = w_mask . y^T + b_mask + x ----------------
// grid (NN/64, BB), block 256; BOTH c-halves per block (opart/Ys staged once, cs loop).
// Ys and Os are disjoint LDS regions (52.5 KB total) -> 2 blocks/CU.
__global__ __launch_bounds__(256) void k_maskout(
        const unsigned short* __restrict__ opart, const float* __restrict__ lsums,
        const float* __restrict__ w_mask, const float* __restrict__ b_mask,
        const float* __restrict__ x, float* __restrict__ out) {
    __shared__ __align__(16) unsigned char pool[52480];
    unsigned short (*Ys)[136] = (unsigned short (*)[136])pool;   // 64x136x2B = 17408
    float (*Os)[68] = (float (*)[68])(pool + 17408);             // 128x68x4B = 34816
    float* invl = (float*)(pool + 52224);                        // 256 B
    int nb = blockIdx.x * 64, b = blockIdx.y;
    int t = threadIdx.x, lane = t & 63, wave = t >> 6;
    int l16 = lane & 15, l4 = lane >> 4;

    const unsigned short* o0 = opart + ((size_t)b * NN + nb) * DD;
    const unsigned short* o1 = opart + (((size_t)BB + b) * NN + nb) * DD;
    if (t < 64) {
        float ls0 = lsums[(size_t)b * NN + nb + t];
        float ls1 = lsums[((size_t)BB + b) * NN + nb + t];
        invl[t] = 1.0f / (ls0 + ls1);
    }
    __syncthreads();
#pragma unroll
    for (int i = 0; i < 4; i++) {  // combine the 2 key-split partials while staging y
        int idx = t + 256 * i;
        int nr = idx >> 4, d0 = (idx & 15) * 8;
        short8 a = *(const short8*)(o0 + (size_t)nr * DD + d0);
        short8 c = *(const short8*)(o1 + (size_t)nr * DD + d0);
        float inv = invl[nr];
        short8 yv;
#pragma unroll
        for (int j = 0; j < 8; j++)
            yv[j] = (short)f2bf((bf2f((unsigned short)a[j]) + bf2f((unsigned short)c[j])) * inv);
        *(short8*)&Ys[nr][d0] = yv;
    }
    __syncthreads();

    for (int cs = 0; cs < 2; cs++) {
        f32x4 acc[2][4];
#pragma unroll
        for (int mf = 0; mf < 2; mf++)
#pragma unroll
            for (int nf = 0; nf < 4; nf++)
#pragma unroll
                for (int e = 0; e < 4; e++) acc[mf][nf][e] = 0.f;

#pragma unroll
        for (int kc = 0; kc < 4; kc++) {
            int d0 = kc * 32 + l4 * 8;
            short8 af[2];
#pragma unroll
            for (int mf = 0; mf < 2; mf++) {
                int c = cs * 128 + wave * 32 + mf * 16 + l16;
                const float* wp = w_mask + c * DD + d0;
                af[mf] = pack8(*(const float4*)wp, *(const float4*)(wp + 4));
            }
#pragma unroll
            for (int nf = 0; nf < 4; nf++) {
                short8 bfr = *(const short8*)&Ys[nf * 16 + l16][d0];
#pragma unroll
                for (int mf = 0; mf < 2; mf++)
                    acc[mf][nf] = __builtin_amdgcn_mfma_f32_16x16x32_bf16(af[mf], bfr, acc[mf][nf], 0, 0, 0);
            }
        }
        __syncthreads();  // cs=1: previous epilogue's Os reads done (no-op cost at cs=0)

        // stage acc + bias into Os[128][68] fp32
#pragma unroll
        for (int mf = 0; mf < 2; mf++) {
            int c0 = wave * 32 + mf * 16 + l4 * 4;  // local c 0..127
            float bb[4];
#pragma unroll
            for (int r = 0; r < 4; r++) bb[r] = b_mask[cs * 128 + c0 + r];
#pragma unroll
            for (int r = 0; r < 4; r++)
#pragma unroll
                for (int nf = 0; nf < 4; nf++)
                    Os[c0 + r][nf * 16 + l16] = acc[mf][nf][r] + bb[r];
        }
        __syncthreads();

        // vectorized epilogue: out = Os + x (float4; 256B contiguous per c-row)
        const float* xp = x + (size_t)b * CC * NN + (size_t)cs * 128 * NN + nb;
        float* op = out + (size_t)b * CC * NN + (size_t)cs * 128 * NN + nb;
#pragma unroll
        for (int i = 0; i < 8; i++) {
            int idx = t + 256 * i;        // 0..2047
            int c = idx >> 4, nq = (idx & 15) * 4;
            float4 osv = *(const float4*)&Os[c][nq];
            float4 xv = *(const float4*)(xp + (size_t)c * NN + nq);
            float4 ov;
            ov.x = osv.x + xv.x; ov.y = osv.y + xv.y;
            ov.z = osv.z + xv.z; ov.w = osv.w + xv.w;
            *(float4*)(op + (size_t)c * NN + nq) = ov;
        }
    }
}

extern "C" void kernel_launch(void* const* d_in, const int* in_sizes, int n_in,
                              void* d_out, int out_size, void* d_ws, size_t ws_size,
                              hipStream_t stream) {
    const float* x       = (const float*)d_in[0];
    const float* w_phi   = (const float*)d_in[1];
    const float* b_phi   = (const float*)d_in[2];
    const float* w_theta = (const float*)d_in[3];
    const float* b_theta = (const float*)d_in[4];
    const float* w_g     = (const float*)d_in[5];
    const float* b_g     = (const float*)d_in[6];
    const float* w_mask  = (const float*)d_in[7];
    const float* b_mask  = (const float*)d_in[8];
    float* out = (float*)d_out;

    // ws (48 MiB): [0,16M): Opart (2*8*4096*128 bf16 = 16 MiB)
    //              [16,24M): Q | [24,32M): K | [32,40M): Vt | [40M+): lsums (256 KiB)
    char* ws = (char*)d_ws;
    unsigned short* opart = (unsigned short*)(ws);
    unsigned short* qw    = (unsigned short*)(ws + ((size_t)16 << 20));
    unsigned short* kw    = (unsigned short*)(ws + ((size_t)24 << 20));
    unsigned short* vtw   = (unsigned short*)(ws + ((size_t)32 << 20));
    float*          lsums = (float*)(ws + ((size_t)40 << 20));

    k_proj<<<dim3(NN / 128, BB), 512, 0, stream>>>(x, w_phi, b_phi, w_theta, b_theta,
                                                   w_g, b_g, qw, kw, vtw);
    k_flash<<<dim3(512, 1, 1), 256, 0, stream>>>(qw, kw, vtw, opart, lsums);
    k_maskout<<<dim3(NN / 64, BB), 256, 0, stream>>>(opart, lsums, w_mask, b_mask, x, out);
}